// Round 6
// baseline (1402.179 us; speedup 1.0000x reference)
//
#include <hip/hip_runtime.h>
#include <hip/hip_bf16.h>

#define N_NODES 100000
#define N_EDGES 1600000
#define N_GRAPHS 512
#define NTILES (N_NODES / 16)          // 6250, exact
#define BSHIFT 9
#define NBUCK ((N_NODES + 511) >> 9)   // 196
#define BCAP 16384

typedef __hip_bfloat16 bf16;
typedef unsigned int uint;
typedef unsigned short ushort;
typedef __attribute__((ext_vector_type(8))) short short8;
typedef __attribute__((ext_vector_type(4))) float float4v;

__device__ __forceinline__ float b2f(bf16 v) { return __bfloat162float(v); }
__device__ __forceinline__ bf16 f2b(float v) { return __float2bfloat16(v); }

__device__ __forceinline__ float ldf(const void* p, long i, int isf32) {
    return isf32 ? ((const float*)p)[i] : b2f(((const bf16*)p)[i]);
}
__device__ __forceinline__ int geti(const int* p, long i, int is64) {
    return is64 ? p[2 * i] : p[i];
}
__device__ __forceinline__ float bflo(uint u) { return __uint_as_float(u << 16); }
__device__ __forceinline__ float bfhi(uint u) { return __uint_as_float(u & 0xffff0000u); }
__device__ __forceinline__ uint packbf(float x, float y) {
    bf16 a = f2b(x), b = f2b(y);
    ushort ua = *(ushort*)&a, ub = *(ushort*)&b;
    return (uint)ua | ((uint)ub << 16);
}

// ---------------- dtype detection ----------------
__global__ void k_detect(const void* __restrict__ x, const int* __restrict__ ei,
                         int* __restrict__ flags) {
    if (threadIdx.x != 0 || blockIdx.x != 0) return;
    const ushort* xu = (const ushort*)x;
    int plaus = 0;
    for (int i = 0; i < 256; i++) {
        ushort u = xu[2 * i];
        int e = (u >> 7) & 0xFF;
        if (u == 0 || (e >= 116 && e <= 132)) plaus++;
    }
    flags[0] = (plaus < 128) ? 1 : 0;          // 1 => fp32 inputs
    int nz = 0;
    for (int i = 0; i < 128; i++) if (ei[2 * i + 1] != 0) nz++;
    flags[1] = (nz < 8) ? 1 : 0;               // 1 => int64 indices
}

// ---------------- bucketed CSR build ----------------
__global__ void k_bin(const int* __restrict__ ei, const int* __restrict__ flags,
                      int* __restrict__ bcnt, uint* __restrict__ bstore) {
    int e = blockIdx.x * blockDim.x + threadIdx.x;
    if (e >= N_EDGES) return;
    int i64 = flags[1];
    int r = geti(ei, e, i64);
    int c = geti(ei, (long)N_EDGES + e, i64);
    int b = c >> BSHIFT;
    int pos = atomicAdd(&bcnt[b], 1);
    if (pos < BCAP) bstore[(long)b * BCAP + pos] = ((uint)r << BSHIFT) | (uint)(c & 511);
}

__global__ __launch_bounds__(256) void k_degb(const int* __restrict__ bcnt,
                                              const uint* __restrict__ bstore,
                                              int* __restrict__ deg) {
    __shared__ int cnt[512];
    int b = blockIdx.x, tid = threadIdx.x;
    cnt[tid] = 0; cnt[tid + 256] = 0;
    __syncthreads();
    int m = bcnt[b]; if (m > BCAP) m = BCAP;
    const uint* bs = bstore + (long)b * BCAP;
    for (int i = tid; i < m; i += 256) atomicAdd(&cnt[bs[i] & 511], 1);
    __syncthreads();
    int n0 = b << BSHIFT;
    for (int t = tid; t < 512; t += 256) {
        int n = n0 + t;
        if (n < N_NODES) deg[n] = cnt[t];
    }
}

__global__ __launch_bounds__(256) void k_scatterb(const int* __restrict__ bcnt,
                                                  const uint* __restrict__ bstore,
                                                  int* __restrict__ row_pos,
                                                  int* __restrict__ csr_src) {
    __shared__ int rp[512];
    int b = blockIdx.x, tid = threadIdx.x;
    int n0 = b << BSHIFT;
    for (int t = tid; t < 512; t += 256) {
        int n = n0 + t;
        rp[t] = (n < N_NODES) ? row_pos[n] : 0;
    }
    __syncthreads();
    int m = bcnt[b]; if (m > BCAP) m = BCAP;
    const uint* bs = bstore + (long)b * BCAP;
    for (int i = tid; i < m; i += 256) {
        uint p = bs[i];
        int pos = atomicAdd(&rp[p & 511], 1);
        csr_src[pos] = (int)(p >> BSHIFT);
    }
    __syncthreads();
    for (int t = tid; t < 512; t += 256) {
        int n = n0 + t;
        if (n < N_NODES) row_pos[n] = rp[t];   // now row ends
    }
}

__global__ void k_dinv(const int* __restrict__ deg, float* __restrict__ dinv) {
    int n = blockIdx.x * blockDim.x + threadIdx.x;
    if (n < N_NODES) dinv[n] = rsqrtf((float)deg[n] + 1.0f);
}

// ---------------- scan (row starts) ----------------
__global__ __launch_bounds__(256) void k_scan_block(const int* __restrict__ deg,
                                                    int* __restrict__ excl,
                                                    int* __restrict__ bsum) {
    __shared__ int tmp[256];
    int tid = threadIdx.x;
    int i = blockIdx.x * 256 + tid;
    int v = (i < N_NODES) ? deg[i] : 0;
    tmp[tid] = v;
    __syncthreads();
    for (int off = 1; off < 256; off <<= 1) {
        int t = (tid >= off) ? tmp[tid - off] : 0;
        __syncthreads();
        tmp[tid] += t;
        __syncthreads();
    }
    if (i < N_NODES) excl[i] = tmp[tid] - v;
    if (tid == 255) bsum[blockIdx.x] = tmp[255];
}

__global__ __launch_bounds__(512) void k_scan_bsum(int* __restrict__ bsum, int nb) {
    __shared__ int tmp[512];
    int tid = threadIdx.x;
    int v = (tid < nb) ? bsum[tid] : 0;
    tmp[tid] = v;
    __syncthreads();
    for (int off = 1; off < 512; off <<= 1) {
        int t = (tid >= off) ? tmp[tid - off] : 0;
        __syncthreads();
        tmp[tid] += t;
        __syncthreads();
    }
    if (tid < nb) bsum[tid] = tmp[tid] - v;
}

__global__ void k_scan_add(int* __restrict__ excl, const int* __restrict__ bsum) {
    int i = blockIdx.x * 256 + threadIdx.x;
    if (i < N_NODES) excl[i] += bsum[blockIdx.x];
}

// ---------------- MFMA node-linear ----------------
// out[n][ooff+f] = act( (scale? dinv[n]:1) * (A[n,:]@W[:,f]) + bias[f] )
template <int K, int KA, int AMODE, int BIAS, int ACT, int SCALE, int OUTF32>
__global__ __launch_bounds__(256) void k_mm(const void* __restrict__ A0,
                                            const void* __restrict__ A1,
                                            const void* __restrict__ W,
                                            const void* __restrict__ Bv,
                                            const float* __restrict__ dinv,
                                            const int* __restrict__ flags,
                                            long w_off, long b_off,
                                            void* __restrict__ outp,
                                            long orow, long ooff) {
    __shared__ short wT[64 * (K + 8)];
    __shared__ float bl[64];
    const int isf32 = flags[0];
    const int tid = threadIdx.x;
    for (int i = tid; i < 64 * K; i += 256) {
        int k = i >> 6, f = i & 63;          // coalesced W read order
        float v = (k < KA) ? ldf(W, w_off + i, isf32) : 0.f;
        bf16 h = f2b(v);
        wT[f * (K + 8) + k] = *(short*)&h;
    }
    if (BIAS && tid < 64) bl[tid] = ldf(Bv, b_off + tid, isf32);
    __syncthreads();

    const int lane = tid & 63, wv = tid >> 6;
    const int m = lane & 15, quad = lane >> 4;

    short8 bfr[4][K / 32];
    #pragma unroll
    for (int cb = 0; cb < 4; cb++)
        #pragma unroll
        for (int ks = 0; ks < K / 32; ks++)
            bfr[cb][ks] = *(const short8*)&wT[(cb * 16 + m) * (K + 8) + ks * 32 + quad * 8];

    for (int t = blockIdx.x * 4 + wv; t < NTILES; t += gridDim.x * 4) {
        const int n0 = t * 16;
        short8 af[K / 32];
        if constexpr (AMODE == 0) {
            const bf16* Ab = (const bf16*)A0;
            #pragma unroll
            for (int ks = 0; ks < K / 32; ks++)
                af[ks] = *(const short8*)&Ab[(long)(n0 + m) * K + ks * 32 + quad * 8];
        } else if constexpr (AMODE == 2) {
            const bf16* Xb = (const bf16*)A0;
            const bf16* Sb = (const bf16*)A1;
            #pragma unroll
            for (int ks = 0; ks < 4; ks++) {
                const bf16* base = (ks < 2) ? &Xb[(long)(n0 + m) * 64 + ks * 32]
                                            : &Sb[(long)(n0 + m) * 64 + (ks - 2) * 32];
                af[ks] = *(const short8*)&base[quad * 8];
            }
        } else {
            if (isf32) {
                const float* Af = (const float*)A0 + (long)(n0 + m) * KA;
                #pragma unroll
                for (int ks = 0; ks < K / 32; ks++) {
                    short8 a;
                    #pragma unroll
                    for (int j = 0; j < 8; j++) {
                        int k = ks * 32 + quad * 8 + j;
                        float v = (KA % 32 == 0 || k < KA) ? Af[k] : 0.f;
                        bf16 h = f2b(v);
                        a[j] = *(short*)&h;
                    }
                    af[ks] = a;
                }
            } else {
                const bf16* Ab = (const bf16*)A0 + (long)(n0 + m) * KA;
                #pragma unroll
                for (int ks = 0; ks < K / 32; ks++) {
                    if constexpr (KA % 32 == 0) {
                        af[ks] = *(const short8*)&Ab[ks * 32 + quad * 8];
                    } else {
                        short8 a;
                        #pragma unroll
                        for (int j = 0; j < 8; j++) {
                            int k = ks * 32 + quad * 8 + j;
                            float v = (k < KA) ? b2f(Ab[k]) : 0.f;
                            bf16 h = f2b(v);
                            a[j] = *(short*)&h;
                        }
                        af[ks] = a;
                    }
                }
            }
        }
        float4v c[4];
        #pragma unroll
        for (int cb = 0; cb < 4; cb++) { c[cb][0] = 0.f; c[cb][1] = 0.f; c[cb][2] = 0.f; c[cb][3] = 0.f; }
        #pragma unroll
        for (int ks = 0; ks < K / 32; ks++)
            #pragma unroll
            for (int cb = 0; cb < 4; cb++)
                c[cb] = __builtin_amdgcn_mfma_f32_16x16x32_bf16(af[ks], bfr[cb][ks], c[cb], 0, 0, 0);
        #pragma unroll
        for (int cb = 0; cb < 4; cb++) {
            int feat = cb * 16 + m;
            float bb = BIAS ? bl[feat] : 0.f;
            #pragma unroll
            for (int r = 0; r < 4; r++) {
                int n = n0 + quad * 4 + r;
                float v = c[cb][r] + bb;
                if (SCALE) v *= dinv[n];
                if (ACT) v = fmaxf(v, 0.f);
                if (OUTF32) ((float*)outp)[(long)n * orow + ooff + feat] = v;
                else ((bf16*)outp)[(long)n * orow + ooff + feat] = f2b(v);
            }
        }
    }
}

// ---------------- fused GIN+GCN gather ----------------
// zsw row (64 uints): [0..31] = z bf16-pairs, [32..63] = swd bf16-pairs.
// lanes<32:  hB[n] = relu(z[n] + sum z[src] + b1)
// lanes>=32: sA[n] = tanh(dinv[n]*(swd[n] + sum swd[src]) + bg)
__global__ __launch_bounds__(256) void k_gather2(const uint* __restrict__ zsw,
                                                 const int* __restrict__ row_end,
                                                 const int* __restrict__ deg,
                                                 const int* __restrict__ csr_src,
                                                 const void* __restrict__ b1,
                                                 const void* __restrict__ bg,
                                                 const float* __restrict__ dinv,
                                                 const int* __restrict__ flags,
                                                 long b_off,
                                                 uint* __restrict__ hB,
                                                 uint* __restrict__ sOut) {
    int tid = threadIdx.x;
    int wv = tid >> 6, lane = tid & 63;
    int half = lane >> 5, fl = lane & 31;
    int isf32 = flags[0];
    float bb0, bb1;
    if (half == 0) {
        bb0 = ldf(b1, b_off + 2 * fl, isf32);
        bb1 = ldf(b1, b_off + 2 * fl + 1, isf32);
    } else {
        bb0 = ldf(bg, b_off + 2 * fl, isf32);
        bb1 = ldf(bg, b_off + 2 * fl + 1, isf32);
    }
    int n = blockIdx.x * 4 + wv;
    if (n >= N_NODES) return;
    int end = row_end[n], beg = end - deg[n];
    uint u = zsw[(long)n * 64 + lane];
    float a0 = bflo(u), a1 = bfhi(u);
    int p = beg;
    for (; p + 8 <= end; p += 8) {
        int i0 = csr_src[p], i1 = csr_src[p + 1], i2 = csr_src[p + 2], i3 = csr_src[p + 3];
        int i4 = csr_src[p + 4], i5 = csr_src[p + 5], i6 = csr_src[p + 6], i7 = csr_src[p + 7];
        uint u0 = zsw[(long)i0 * 64 + lane], u1 = zsw[(long)i1 * 64 + lane];
        uint u2 = zsw[(long)i2 * 64 + lane], u3 = zsw[(long)i3 * 64 + lane];
        uint u4 = zsw[(long)i4 * 64 + lane], u5 = zsw[(long)i5 * 64 + lane];
        uint u6 = zsw[(long)i6 * 64 + lane], u7 = zsw[(long)i7 * 64 + lane];
        a0 += ((bflo(u0) + bflo(u1)) + (bflo(u2) + bflo(u3)))
            + ((bflo(u4) + bflo(u5)) + (bflo(u6) + bflo(u7)));
        a1 += ((bfhi(u0) + bfhi(u1)) + (bfhi(u2) + bfhi(u3)))
            + ((bfhi(u4) + bfhi(u5)) + (bfhi(u6) + bfhi(u7)));
    }
    for (; p < end; p++) {
        uint uu = zsw[(long)csr_src[p] * 64 + lane];
        a0 += bflo(uu); a1 += bfhi(uu);
    }
    if (half == 0) {
        hB[(long)n * 32 + fl] = packbf(fmaxf(a0 + bb0, 0.f), fmaxf(a1 + bb1, 0.f));
    } else {
        float dn = dinv[n];
        sOut[(long)n * 32 + fl] = packbf(tanhf(dn * a0 + bb0), tanhf(dn * a1 + bb1));
    }
}

// ---------------- pool: run-length segmented sum over sorted batch ----------------
__global__ __launch_bounds__(256) void k_pool(const float* __restrict__ xw,
                                              const int* __restrict__ batch,
                                              const int* __restrict__ flags,
                                              float* __restrict__ xp) {
    int tid = threadIdx.x;
    int slot = tid >> 6, lane = tid & 63;
    int nbeg = (blockIdx.x * 4 + slot) * 16;
    if (nbeg >= N_NODES) return;
    int nend = nbeg + 16;
    if (nend > N_NODES) nend = N_NODES;
    int i64 = flags[1];
    int g = geti(batch, nbeg, i64);
    float acc = 0.f;
    for (int n = nbeg; n < nend; n++) {
        int gn = geti(batch, n, i64);
        if (gn != g) { atomicAdd(&xp[(long)g * 64 + lane], acc); acc = 0.f; g = gn; }
        acc += xw[(long)n * 64 + lane];
    }
    atomicAdd(&xp[(long)g * 64 + lane], acc);
}

// ---------------- final: post + readout + log_softmax ----------------
__global__ __launch_bounds__(64) void k_final(const float* __restrict__ xp,
                                              const void* __restrict__ post_w,
                                              const void* __restrict__ post_b,
                                              const void* __restrict__ ro_w,
                                              const void* __restrict__ ro_b,
                                              const int* __restrict__ flags,
                                              void* __restrict__ out) {
    __shared__ float h2[64];
    __shared__ float lg[16];
    int isf32 = flags[0];
    int g = blockIdx.x;
    int f = threadIdx.x;
    float xr = xp[(long)g * 64 + f];
    float acc = ldf(post_b, f, isf32);
    #pragma unroll
    for (int j = 0; j < 64; j++) acc += __shfl(xr, j) * ldf(post_w, j * 64 + f, isf32);
    float v = fmaxf(acc, 0.f);
    h2[f] = v;
    long oxp = (long)g * 64 + f;
    if (isf32) ((float*)out)[oxp] = v; else ((bf16*)out)[oxp] = f2b(v);
    __syncthreads();
    if (f < 16) {
        float a = ldf(ro_b, f, isf32);
        for (int j = 0; j < 64; j++) a += h2[j] * ldf(ro_w, j * 16 + f, isf32);
        lg[f] = a;
    }
    __syncthreads();
    if (f < 16) {
        float m = -1e30f;
        for (int j = 0; j < 16; j++) m = fmaxf(m, lg[j]);
        float sum = 0.f;
        for (int j = 0; j < 16; j++) sum += expf(lg[j] - m);
        long oy = (long)N_GRAPHS * 64 + (long)g * 16 + f;
        float yv = lg[f] - m - logf(sum);
        if (isf32) ((float*)out)[oy] = yv; else ((bf16*)out)[oy] = f2b(yv);
    }
}

extern "C" void kernel_launch(void* const* d_in, const int* in_sizes, int n_in,
                              void* d_out, int out_size, void* d_ws, size_t ws_size,
                              hipStream_t stream) {
    const void* x_in  = d_in[0];
    const void* s_in  = d_in[1];
    const int*  ei    = (const int*)d_in[2];
    const int*  batch = (const int*)d_in[3];
    const void* pre_w = d_in[4];
    const void* pre_b = d_in[5];
    const void* emb_w = d_in[6];
    const void* emb_b = d_in[7];
    const void* gin_w1 = d_in[8];
    const void* gin_b1 = d_in[9];
    const void* gin_w2 = d_in[10];
    const void* gin_b2 = d_in[11];
    const void* gcn_w  = d_in[12];
    const void* gcn_b  = d_in[13];
    const void* whp_w  = d_in[14];
    const void* whp_b  = d_in[15];
    const void* post_w = d_in[16];
    const void* post_b = d_in[17];
    const void* ro_w   = d_in[18];
    const void* ro_b   = d_in[19];

    // ws: flags(64) | deg(N) | row_pos(N) | bsum(512) | bcnt(256) | bstore(NBUCK*BCAP)
    //   | csr_src(E) | dinv(N) | x0,x1,sA,hB (bf16 N*64) | zsw (uint N*64) | wout (f32 N*64) | xp
    int* flags   = (int*)d_ws;
    int* deg     = flags + 64;
    int* row_pos = deg + N_NODES;
    int* bsum    = row_pos + N_NODES;
    int* bcnt    = bsum + 512;
    uint* bstore = (uint*)(bcnt + 256);
    int* csr_src = (int*)(bstore + (long)NBUCK * BCAP);
    float* dinv  = (float*)(csr_src + N_EDGES);
    bf16* x0     = (bf16*)(dinv + N_NODES);
    bf16* x1     = x0 + (long)N_NODES * 64;
    bf16* sA     = x1 + (long)N_NODES * 64;
    bf16* hB     = sA + (long)N_NODES * 64;
    uint* zsw    = (uint*)(hB + (long)N_NODES * 64);
    float* wout  = (float*)(zsw + (long)N_NODES * 64);
    float* xp    = wout + (long)N_NODES * 64;

    const int nbN = (N_NODES + 255) / 256;   // 391
    const int nbE = (N_EDGES + 255) / 256;
    const int MMB = 512;
    const int GGB = (N_NODES + 3) / 4;       // 25000

    k_detect<<<1, 64, 0, stream>>>(x_in, ei, flags);

    // bucketed CSR build
    hipMemsetAsync(bcnt, 0, 256 * sizeof(int), stream);
    k_bin<<<nbE, 256, 0, stream>>>(ei, flags, bcnt, bstore);
    k_degb<<<NBUCK, 256, 0, stream>>>(bcnt, bstore, deg);
    k_dinv<<<nbN, 256, 0, stream>>>(deg, dinv);
    k_scan_block<<<nbN, 256, 0, stream>>>(deg, row_pos, bsum);
    k_scan_bsum<<<1, 512, 0, stream>>>(bsum, nbN);
    k_scan_add<<<nbN, 256, 0, stream>>>(row_pos, bsum);
    k_scatterb<<<NBUCK, 256, 0, stream>>>(bcnt, bstore, row_pos, csr_src);  // row_pos -> ends

    const long W1 = 128 * 64, W2 = 64 * 64, WG = 64 * 64, B = 64;

    // pre / embedding -> bf16 activations
    k_mm<128, 128, 1, 1, 0, 0, 0><<<MMB, 256, 0, stream>>>(x_in, nullptr, pre_w, pre_b, dinv, flags, 0L, 0L, x0, 64, 0);
    k_mm<32, 16, 1, 1, 0, 0, 0><<<MMB, 256, 0, stream>>>(s_in, nullptr, emb_w, emb_b, dinv, flags, 0L, 0L, sA, 64, 0);

    // ---- layer 0: x0 -> x1 ----
    k_mm<128, 128, 2, 0, 0, 0, 0><<<MMB, 256, 0, stream>>>(x0, sA, gin_w1, nullptr, dinv, flags, 0L, 0L, zsw, 128, 0);
    k_mm<64, 64, 0, 0, 0, 1, 0><<<MMB, 256, 0, stream>>>(sA, nullptr, gcn_w, nullptr, dinv, flags, 0L, 0L, zsw, 128, 64);
    k_gather2<<<GGB, 256, 0, stream>>>(zsw, row_pos, deg, csr_src, gin_b1, gcn_b, dinv, flags, 0L, (uint*)hB, (uint*)sA);
    k_mm<64, 64, 0, 1, 1, 0, 0><<<MMB, 256, 0, stream>>>(hB, nullptr, gin_w2, gin_b2, dinv, flags, 0L, 0L, x1, 64, 0);

    // ---- layer 1: x1 -> x0 ----
    k_mm<128, 128, 2, 0, 0, 0, 0><<<MMB, 256, 0, stream>>>(x1, sA, gin_w1, nullptr, dinv, flags, W1, 0L, zsw, 128, 0);
    k_mm<64, 64, 0, 0, 0, 1, 0><<<MMB, 256, 0, stream>>>(sA, nullptr, gcn_w, nullptr, dinv, flags, WG, 0L, zsw, 128, 64);
    k_gather2<<<GGB, 256, 0, stream>>>(zsw, row_pos, deg, csr_src, gin_b1, gcn_b, dinv, flags, B, (uint*)hB, (uint*)sA);
    k_mm<64, 64, 0, 1, 1, 0, 0><<<MMB, 256, 0, stream>>>(hB, nullptr, gin_w2, gin_b2, dinv, flags, W2, B, x0, 64, 0);

    // ---- head ----
    k_mm<128, 128, 2, 1, 0, 0, 1><<<MMB, 256, 0, stream>>>(x0, sA, whp_w, whp_b, dinv, flags, 0L, 0L, wout, 64, 0);
    hipMemsetAsync(xp, 0, (size_t)N_GRAPHS * 64 * sizeof(float), stream);
    k_pool<<<(N_NODES + 63) / 64, 256, 0, stream>>>(wout, batch, flags, xp);

    k_final<<<N_GRAPHS, 64, 0, stream>>>(xp, post_w, post_b, ro_w, ro_b, flags, d_out);
}

// Round 7
// 672.078 us; speedup vs baseline: 2.0863x; 2.0863x over previous
//
#include <hip/hip_runtime.h>
#include <hip/hip_bf16.h>

#define N_NODES 100000
#define N_EDGES 1600000
#define N_GRAPHS 512
#define NTILES (N_NODES / 16)          // 6250, exact

typedef __hip_bfloat16 bf16;
typedef unsigned int uint;
typedef unsigned short ushort;
typedef __attribute__((ext_vector_type(8))) short short8;
typedef __attribute__((ext_vector_type(4))) float float4v;

__device__ __forceinline__ float b2f(bf16 v) { return __bfloat162float(v); }
__device__ __forceinline__ bf16 f2b(float v) { return __float2bfloat16(v); }

__device__ __forceinline__ float ldf(const void* p, long i, int isf32) {
    return isf32 ? ((const float*)p)[i] : b2f(((const bf16*)p)[i]);
}
__device__ __forceinline__ int geti(const int* p, long i, int is64) {
    return is64 ? p[2 * i] : p[i];
}
__device__ __forceinline__ float bflo(uint u) { return __uint_as_float(u << 16); }
__device__ __forceinline__ float bfhi(uint u) { return __uint_as_float(u & 0xffff0000u); }
__device__ __forceinline__ uint packbf(float x, float y) {
    bf16 a = f2b(x), b = f2b(y);
    ushort ua = *(ushort*)&a, ub = *(ushort*)&b;
    return (uint)ua | ((uint)ub << 16);
}

// ---------------- dtype detection ----------------
__global__ void k_detect(const void* __restrict__ x, const int* __restrict__ ei,
                         int* __restrict__ flags) {
    if (threadIdx.x != 0 || blockIdx.x != 0) return;
    const ushort* xu = (const ushort*)x;
    int plaus = 0;
    for (int i = 0; i < 256; i++) {
        ushort u = xu[2 * i];
        int e = (u >> 7) & 0xFF;
        if (u == 0 || (e >= 116 && e <= 132)) plaus++;
    }
    flags[0] = (plaus < 128) ? 1 : 0;          // 1 => fp32 inputs
    int nz = 0;
    for (int i = 0; i < 128; i++) if (ei[2 * i + 1] != 0) nz++;
    flags[1] = (nz < 8) ? 1 : 0;               // 1 => int64 indices
}

// ---------------- degree / dinv (direct atomics: 100K addresses, low contention) ----------------
__global__ void k_deg(const int* __restrict__ ei, const int* __restrict__ flags,
                      int* __restrict__ deg) {
    int e = blockIdx.x * blockDim.x + threadIdx.x;
    if (e < N_EDGES) atomicAdd(&deg[geti(ei, (long)N_EDGES + e, flags[1])], 1);
}

__global__ void k_dinv(const int* __restrict__ deg, float* __restrict__ dinv) {
    int n = blockIdx.x * blockDim.x + threadIdx.x;
    if (n < N_NODES) dinv[n] = rsqrtf((float)deg[n] + 1.0f);
}

// ---------------- scan (row starts) ----------------
__global__ __launch_bounds__(256) void k_scan_block(const int* __restrict__ deg,
                                                    int* __restrict__ excl,
                                                    int* __restrict__ bsum) {
    __shared__ int tmp[256];
    int tid = threadIdx.x;
    int i = blockIdx.x * 256 + tid;
    int v = (i < N_NODES) ? deg[i] : 0;
    tmp[tid] = v;
    __syncthreads();
    for (int off = 1; off < 256; off <<= 1) {
        int t = (tid >= off) ? tmp[tid - off] : 0;
        __syncthreads();
        tmp[tid] += t;
        __syncthreads();
    }
    if (i < N_NODES) excl[i] = tmp[tid] - v;
    if (tid == 255) bsum[blockIdx.x] = tmp[255];
}

__global__ __launch_bounds__(512) void k_scan_bsum(int* __restrict__ bsum, int nb) {
    __shared__ int tmp[512];
    int tid = threadIdx.x;
    int v = (tid < nb) ? bsum[tid] : 0;
    tmp[tid] = v;
    __syncthreads();
    for (int off = 1; off < 512; off <<= 1) {
        int t = (tid >= off) ? tmp[tid - off] : 0;
        __syncthreads();
        tmp[tid] += t;
        __syncthreads();
    }
    if (tid < nb) bsum[tid] = tmp[tid] - v;
}

__global__ void k_scan_add(int* __restrict__ excl, const int* __restrict__ bsum) {
    int i = blockIdx.x * 256 + threadIdx.x;
    if (i < N_NODES) excl[i] += bsum[blockIdx.x];
}

// direct CSR bucket: write-amplified but bandwidth-bound (~137us) — beats
// any same-address-atomic binning scheme (round-6 lesson)
__global__ void k_build_csr(const int* __restrict__ ei, const int* __restrict__ flags,
                            int* __restrict__ row_pos, int* __restrict__ csr_src) {
    int e = blockIdx.x * blockDim.x + threadIdx.x;
    if (e >= N_EDGES) return;
    int i64 = flags[1];
    int r = geti(ei, e, i64);
    int c = geti(ei, (long)N_EDGES + e, i64);
    int pos = atomicAdd(&row_pos[c], 1);
    csr_src[pos] = r;
}

// ---------------- MFMA node-linear ----------------
// out[n][ooff+f] = act( (scale? dinv[n]:1) * (A[n,:]@W[:,f]) + bias[f] )
template <int K, int KA, int AMODE, int BIAS, int ACT, int SCALE, int OUTF32>
__global__ __launch_bounds__(256) void k_mm(const void* __restrict__ A0,
                                            const void* __restrict__ A1,
                                            const void* __restrict__ W,
                                            const void* __restrict__ Bv,
                                            const float* __restrict__ dinv,
                                            const int* __restrict__ flags,
                                            long w_off, long b_off,
                                            void* __restrict__ outp,
                                            long orow, long ooff) {
    __shared__ short wT[64 * (K + 8)];
    __shared__ float bl[64];
    const int isf32 = flags[0];
    const int tid = threadIdx.x;
    for (int i = tid; i < 64 * K; i += 256) {
        int k = i >> 6, f = i & 63;          // coalesced W read order
        float v = (k < KA) ? ldf(W, w_off + i, isf32) : 0.f;
        bf16 h = f2b(v);
        wT[f * (K + 8) + k] = *(short*)&h;
    }
    if (BIAS && tid < 64) bl[tid] = ldf(Bv, b_off + tid, isf32);
    __syncthreads();

    const int lane = tid & 63, wv = tid >> 6;
    const int m = lane & 15, quad = lane >> 4;

    short8 bfr[4][K / 32];
    #pragma unroll
    for (int cb = 0; cb < 4; cb++)
        #pragma unroll
        for (int ks = 0; ks < K / 32; ks++)
            bfr[cb][ks] = *(const short8*)&wT[(cb * 16 + m) * (K + 8) + ks * 32 + quad * 8];

    for (int t = blockIdx.x * 4 + wv; t < NTILES; t += gridDim.x * 4) {
        const int n0 = t * 16;
        short8 af[K / 32];
        if constexpr (AMODE == 0) {
            const bf16* Ab = (const bf16*)A0;
            #pragma unroll
            for (int ks = 0; ks < K / 32; ks++)
                af[ks] = *(const short8*)&Ab[(long)(n0 + m) * K + ks * 32 + quad * 8];
        } else if constexpr (AMODE == 2) {
            const bf16* Xb = (const bf16*)A0;
            const bf16* Sb = (const bf16*)A1;
            #pragma unroll
            for (int ks = 0; ks < 4; ks++) {
                const bf16* base = (ks < 2) ? &Xb[(long)(n0 + m) * 64 + ks * 32]
                                            : &Sb[(long)(n0 + m) * 64 + (ks - 2) * 32];
                af[ks] = *(const short8*)&base[quad * 8];
            }
        } else {
            if (isf32) {
                const float* Af = (const float*)A0 + (long)(n0 + m) * KA;
                #pragma unroll
                for (int ks = 0; ks < K / 32; ks++) {
                    short8 a;
                    #pragma unroll
                    for (int j = 0; j < 8; j++) {
                        int k = ks * 32 + quad * 8 + j;
                        float v = (KA % 32 == 0 || k < KA) ? Af[k] : 0.f;
                        bf16 h = f2b(v);
                        a[j] = *(short*)&h;
                    }
                    af[ks] = a;
                }
            } else {
                const bf16* Ab = (const bf16*)A0 + (long)(n0 + m) * KA;
                #pragma unroll
                for (int ks = 0; ks < K / 32; ks++) {
                    if constexpr (KA % 32 == 0) {
                        af[ks] = *(const short8*)&Ab[ks * 32 + quad * 8];
                    } else {
                        short8 a;
                        #pragma unroll
                        for (int j = 0; j < 8; j++) {
                            int k = ks * 32 + quad * 8 + j;
                            float v = (k < KA) ? b2f(Ab[k]) : 0.f;
                            bf16 h = f2b(v);
                            a[j] = *(short*)&h;
                        }
                        af[ks] = a;
                    }
                }
            }
        }
        float4v c[4];
        #pragma unroll
        for (int cb = 0; cb < 4; cb++) { c[cb][0] = 0.f; c[cb][1] = 0.f; c[cb][2] = 0.f; c[cb][3] = 0.f; }
        #pragma unroll
        for (int ks = 0; ks < K / 32; ks++)
            #pragma unroll
            for (int cb = 0; cb < 4; cb++)
                c[cb] = __builtin_amdgcn_mfma_f32_16x16x32_bf16(af[ks], bfr[cb][ks], c[cb], 0, 0, 0);
        #pragma unroll
        for (int cb = 0; cb < 4; cb++) {
            int feat = cb * 16 + m;
            float bb = BIAS ? bl[feat] : 0.f;
            #pragma unroll
            for (int r = 0; r < 4; r++) {
                int n = n0 + quad * 4 + r;
                float v = c[cb][r] + bb;
                if (SCALE) v *= dinv[n];
                if (ACT) v = fmaxf(v, 0.f);
                if (OUTF32) ((float*)outp)[(long)n * orow + ooff + feat] = v;
                else ((bf16*)outp)[(long)n * orow + ooff + feat] = f2b(v);
            }
        }
    }
}

// ---------------- fused GIN+GCN gather ----------------
// zsw row (64 uints): [0..31] = z bf16-pairs, [32..63] = swd bf16-pairs.
// lanes<32:  hB[n] = relu(z[n] + sum z[src] + b1)
// lanes>=32: sA[n] = tanh(dinv[n]*(swd[n] + sum swd[src]) + bg)
__global__ __launch_bounds__(256) void k_gather2(const uint* __restrict__ zsw,
                                                 const int* __restrict__ row_end,
                                                 const int* __restrict__ deg,
                                                 const int* __restrict__ csr_src,
                                                 const void* __restrict__ b1,
                                                 const void* __restrict__ bg,
                                                 const float* __restrict__ dinv,
                                                 const int* __restrict__ flags,
                                                 long b_off,
                                                 uint* __restrict__ hB,
                                                 uint* __restrict__ sOut) {
    int tid = threadIdx.x;
    int wv = tid >> 6, lane = tid & 63;
    int half = lane >> 5, fl = lane & 31;
    int isf32 = flags[0];
    float bb0, bb1;
    if (half == 0) {
        bb0 = ldf(b1, b_off + 2 * fl, isf32);
        bb1 = ldf(b1, b_off + 2 * fl + 1, isf32);
    } else {
        bb0 = ldf(bg, b_off + 2 * fl, isf32);
        bb1 = ldf(bg, b_off + 2 * fl + 1, isf32);
    }
    int n = blockIdx.x * 4 + wv;
    if (n >= N_NODES) return;
    int end = row_end[n], beg = end - deg[n];
    uint u = zsw[(long)n * 64 + lane];
    float a0 = bflo(u), a1 = bfhi(u);
    int p = beg;
    for (; p + 8 <= end; p += 8) {
        int i0 = csr_src[p], i1 = csr_src[p + 1], i2 = csr_src[p + 2], i3 = csr_src[p + 3];
        int i4 = csr_src[p + 4], i5 = csr_src[p + 5], i6 = csr_src[p + 6], i7 = csr_src[p + 7];
        uint u0 = zsw[(long)i0 * 64 + lane], u1 = zsw[(long)i1 * 64 + lane];
        uint u2 = zsw[(long)i2 * 64 + lane], u3 = zsw[(long)i3 * 64 + lane];
        uint u4 = zsw[(long)i4 * 64 + lane], u5 = zsw[(long)i5 * 64 + lane];
        uint u6 = zsw[(long)i6 * 64 + lane], u7 = zsw[(long)i7 * 64 + lane];
        a0 += ((bflo(u0) + bflo(u1)) + (bflo(u2) + bflo(u3)))
            + ((bflo(u4) + bflo(u5)) + (bflo(u6) + bflo(u7)));
        a1 += ((bfhi(u0) + bfhi(u1)) + (bfhi(u2) + bfhi(u3)))
            + ((bfhi(u4) + bfhi(u5)) + (bfhi(u6) + bfhi(u7)));
    }
    for (; p < end; p++) {
        uint uu = zsw[(long)csr_src[p] * 64 + lane];
        a0 += bflo(uu); a1 += bfhi(uu);
    }
    if (half == 0) {
        hB[(long)n * 32 + fl] = packbf(fmaxf(a0 + bb0, 0.f), fmaxf(a1 + bb1, 0.f));
    } else {
        float dn = dinv[n];
        sOut[(long)n * 32 + fl] = packbf(tanhf(dn * a0 + bb0), tanhf(dn * a1 + bb1));
    }
}

// ---------------- pool: run-length segmented sum over sorted batch ----------------
__global__ __launch_bounds__(256) void k_pool(const float* __restrict__ xw,
                                              const int* __restrict__ batch,
                                              const int* __restrict__ flags,
                                              float* __restrict__ xp) {
    int tid = threadIdx.x;
    int slot = tid >> 6, lane = tid & 63;
    int nbeg = (blockIdx.x * 4 + slot) * 16;
    if (nbeg >= N_NODES) return;
    int nend = nbeg + 16;
    if (nend > N_NODES) nend = N_NODES;
    int i64 = flags[1];
    int g = geti(batch, nbeg, i64);
    float acc = 0.f;
    for (int n = nbeg; n < nend; n++) {
        int gn = geti(batch, n, i64);
        if (gn != g) { atomicAdd(&xp[(long)g * 64 + lane], acc); acc = 0.f; g = gn; }
        acc += xw[(long)n * 64 + lane];
    }
    atomicAdd(&xp[(long)g * 64 + lane], acc);
}

// ---------------- final: post + readout + log_softmax ----------------
__global__ __launch_bounds__(64) void k_final(const float* __restrict__ xp,
                                              const void* __restrict__ post_w,
                                              const void* __restrict__ post_b,
                                              const void* __restrict__ ro_w,
                                              const void* __restrict__ ro_b,
                                              const int* __restrict__ flags,
                                              void* __restrict__ out) {
    __shared__ float h2[64];
    __shared__ float lg[16];
    int isf32 = flags[0];
    int g = blockIdx.x;
    int f = threadIdx.x;
    float xr = xp[(long)g * 64 + f];
    float acc = ldf(post_b, f, isf32);
    #pragma unroll
    for (int j = 0; j < 64; j++) acc += __shfl(xr, j) * ldf(post_w, j * 64 + f, isf32);
    float v = fmaxf(acc, 0.f);
    h2[f] = v;
    long oxp = (long)g * 64 + f;
    if (isf32) ((float*)out)[oxp] = v; else ((bf16*)out)[oxp] = f2b(v);
    __syncthreads();
    if (f < 16) {
        float a = ldf(ro_b, f, isf32);
        for (int j = 0; j < 64; j++) a += h2[j] * ldf(ro_w, j * 16 + f, isf32);
        lg[f] = a;
    }
    __syncthreads();
    if (f < 16) {
        float m = -1e30f;
        for (int j = 0; j < 16; j++) m = fmaxf(m, lg[j]);
        float sum = 0.f;
        for (int j = 0; j < 16; j++) sum += expf(lg[j] - m);
        long oy = (long)N_GRAPHS * 64 + (long)g * 16 + f;
        float yv = lg[f] - m - logf(sum);
        if (isf32) ((float*)out)[oy] = yv; else ((bf16*)out)[oy] = f2b(yv);
    }
}

extern "C" void kernel_launch(void* const* d_in, const int* in_sizes, int n_in,
                              void* d_out, int out_size, void* d_ws, size_t ws_size,
                              hipStream_t stream) {
    const void* x_in  = d_in[0];
    const void* s_in  = d_in[1];
    const int*  ei    = (const int*)d_in[2];
    const int*  batch = (const int*)d_in[3];
    const void* pre_w = d_in[4];
    const void* pre_b = d_in[5];
    const void* emb_w = d_in[6];
    const void* emb_b = d_in[7];
    const void* gin_w1 = d_in[8];
    const void* gin_b1 = d_in[9];
    const void* gin_w2 = d_in[10];
    const void* gin_b2 = d_in[11];
    const void* gcn_w  = d_in[12];
    const void* gcn_b  = d_in[13];
    const void* whp_w  = d_in[14];
    const void* whp_b  = d_in[15];
    const void* post_w = d_in[16];
    const void* post_b = d_in[17];
    const void* ro_w   = d_in[18];
    const void* ro_b   = d_in[19];

    // ws: flags(64) | deg(N) | row_pos(N) | bsum(512) | csr_src(E) | dinv(N)
    //   | x0,x1,sA,hB (bf16 N*64) | zsw (uint N*64) | wout (f32 N*64) | xp
    int* flags   = (int*)d_ws;
    int* deg     = flags + 64;
    int* row_pos = deg + N_NODES;
    int* bsum    = row_pos + N_NODES;
    int* csr_src = bsum + 512;
    float* dinv  = (float*)(csr_src + N_EDGES);
    bf16* x0     = (bf16*)(dinv + N_NODES);
    bf16* x1     = x0 + (long)N_NODES * 64;
    bf16* sA     = x1 + (long)N_NODES * 64;
    bf16* hB     = sA + (long)N_NODES * 64;
    uint* zsw    = (uint*)(hB + (long)N_NODES * 64);
    float* wout  = (float*)(zsw + (long)N_NODES * 64);
    float* xp    = wout + (long)N_NODES * 64;

    const int nbN = (N_NODES + 255) / 256;   // 391
    const int nbE = (N_EDGES + 255) / 256;
    const int MMB = 512;
    const int GGB = (N_NODES + 3) / 4;       // 25000

    k_detect<<<1, 64, 0, stream>>>(x_in, ei, flags);

    // CSR + dinv (direct build — bandwidth-bound, not atomic-serialized)
    hipMemsetAsync(deg, 0, N_NODES * sizeof(int), stream);
    k_deg<<<nbE, 256, 0, stream>>>(ei, flags, deg);
    k_dinv<<<nbN, 256, 0, stream>>>(deg, dinv);
    k_scan_block<<<nbN, 256, 0, stream>>>(deg, row_pos, bsum);
    k_scan_bsum<<<1, 512, 0, stream>>>(bsum, nbN);
    k_scan_add<<<nbN, 256, 0, stream>>>(row_pos, bsum);
    k_build_csr<<<nbE, 256, 0, stream>>>(ei, flags, row_pos, csr_src);  // row_pos -> ends

    const long W1 = 128 * 64, W2 = 64 * 64, WG = 64 * 64, B = 64;

    // pre / embedding -> bf16 activations
    k_mm<128, 128, 1, 1, 0, 0, 0><<<MMB, 256, 0, stream>>>(x_in, nullptr, pre_w, pre_b, dinv, flags, 0L, 0L, x0, 64, 0);
    k_mm<32, 16, 1, 1, 0, 0, 0><<<MMB, 256, 0, stream>>>(s_in, nullptr, emb_w, emb_b, dinv, flags, 0L, 0L, sA, 64, 0);

    // ---- layer 0: x0 -> x1 ----
    k_mm<128, 128, 2, 0, 0, 0, 0><<<MMB, 256, 0, stream>>>(x0, sA, gin_w1, nullptr, dinv, flags, 0L, 0L, zsw, 128, 0);
    k_mm<64, 64, 0, 0, 0, 1, 0><<<MMB, 256, 0, stream>>>(sA, nullptr, gcn_w, nullptr, dinv, flags, 0L, 0L, zsw, 128, 64);
    k_gather2<<<GGB, 256, 0, stream>>>(zsw, row_pos, deg, csr_src, gin_b1, gcn_b, dinv, flags, 0L, (uint*)hB, (uint*)sA);
    k_mm<64, 64, 0, 1, 1, 0, 0><<<MMB, 256, 0, stream>>>(hB, nullptr, gin_w2, gin_b2, dinv, flags, 0L, 0L, x1, 64, 0);

    // ---- layer 1: x1 -> x0 ----
    k_mm<128, 128, 2, 0, 0, 0, 0><<<MMB, 256, 0, stream>>>(x1, sA, gin_w1, nullptr, dinv, flags, W1, 0L, zsw, 128, 0);
    k_mm<64, 64, 0, 0, 0, 1, 0><<<MMB, 256, 0, stream>>>(sA, nullptr, gcn_w, nullptr, dinv, flags, WG, 0L, zsw, 128, 64);
    k_gather2<<<GGB, 256, 0, stream>>>(zsw, row_pos, deg, csr_src, gin_b1, gcn_b, dinv, flags, B, (uint*)hB, (uint*)sA);
    k_mm<64, 64, 0, 1, 1, 0, 0><<<MMB, 256, 0, stream>>>(hB, nullptr, gin_w2, gin_b2, dinv, flags, W2, B, x0, 64, 0);

    // ---- head ----
    k_mm<128, 128, 2, 1, 0, 0, 1><<<MMB, 256, 0, stream>>>(x0, sA, whp_w, whp_b, dinv, flags, 0L, 0L, wout, 64, 0);
    hipMemsetAsync(xp, 0, (size_t)N_GRAPHS * 64 * sizeof(float), stream);
    k_pool<<<(N_NODES + 63) / 64, 256, 0, stream>>>(wout, batch, flags, xp);

    k_final<<<N_GRAPHS, 64, 0, stream>>>(xp, post_w, post_b, ro_w, ro_b, flags, d_out);
}

// Round 8
// 552.496 us; speedup vs baseline: 2.5379x; 1.2164x over previous
//
#include <hip/hip_runtime.h>
#include <hip/hip_bf16.h>

#define N_NODES 100000
#define N_EDGES 1600000
#define N_GRAPHS 512
#define NTILES (N_NODES / 16)          // 6250, exact
#define BSH 9                          // 512 nodes per bucket
#define NBUCK ((N_NODES + 511) >> BSH) // 196
#define NB1 256                        // blocks for hist/scatter passes

typedef __hip_bfloat16 bf16;
typedef unsigned int uint;
typedef unsigned short ushort;
typedef __attribute__((ext_vector_type(8))) short short8;
typedef __attribute__((ext_vector_type(4))) float float4v;

__device__ __forceinline__ float b2f(bf16 v) { return __bfloat162float(v); }
__device__ __forceinline__ bf16 f2b(float v) { return __float2bfloat16(v); }

__device__ __forceinline__ float ldf(const void* p, long i, int isf32) {
    return isf32 ? ((const float*)p)[i] : b2f(((const bf16*)p)[i]);
}
__device__ __forceinline__ int geti(const int* p, long i, int is64) {
    return is64 ? p[2 * i] : p[i];
}
__device__ __forceinline__ float bflo(uint u) { return __uint_as_float(u << 16); }
__device__ __forceinline__ float bfhi(uint u) { return __uint_as_float(u & 0xffff0000u); }
__device__ __forceinline__ uint packbf(float x, float y) {
    bf16 a = f2b(x), b = f2b(y);
    ushort ua = *(ushort*)&a, ub = *(ushort*)&b;
    return (uint)ua | ((uint)ub << 16);
}

// ---------------- dtype detection ----------------
__global__ void k_detect(const void* __restrict__ x, const int* __restrict__ ei,
                         int* __restrict__ flags) {
    if (threadIdx.x != 0 || blockIdx.x != 0) return;
    const ushort* xu = (const ushort*)x;
    int plaus = 0;
    for (int i = 0; i < 256; i++) {
        ushort u = xu[2 * i];
        int e = (u >> 7) & 0xFF;
        if (u == 0 || (e >= 116 && e <= 132)) plaus++;
    }
    flags[0] = (plaus < 128) ? 1 : 0;          // 1 => fp32 inputs
    int nz = 0;
    for (int i = 0; i < 128; i++) if (ei[2 * i + 1] != 0) nz++;
    flags[1] = (nz < 8) ? 1 : 0;               // 1 => int64 indices
}

// ---------------- CSR build: deterministic 2-pass radix partition ----------------
// pass 1: per-block LDS histogram of dest bucket
__global__ __launch_bounds__(256) void k1_hist(const int* __restrict__ ei,
                                               const int* __restrict__ flags,
                                               int* __restrict__ hist) {
    __shared__ int h[NBUCK];
    int tid = threadIdx.x;
    for (int i = tid; i < NBUCK; i += 256) h[i] = 0;
    __syncthreads();
    int i64 = flags[1];
    for (int e = blockIdx.x * 256 + tid; e < N_EDGES; e += NB1 * 256) {
        int c = geti(ei, (long)N_EDGES + e, i64);
        atomicAdd(&h[c >> BSH], 1);
    }
    __syncthreads();
    for (int i = tid; i < NBUCK; i += 256) hist[(long)blockIdx.x * NBUCK + i] = h[i];
}

// per bucket: exclusive scan over the 256 block counts
__global__ __launch_bounds__(256) void k2a(const int* __restrict__ hist,
                                           int* __restrict__ pexcl,
                                           int* __restrict__ total) {
    __shared__ int tmp[256];
    int b = blockIdx.x, t = threadIdx.x;
    int v = hist[(long)t * NBUCK + b];
    tmp[t] = v;
    __syncthreads();
    for (int off = 1; off < 256; off <<= 1) {
        int u = (t >= off) ? tmp[t - off] : 0;
        __syncthreads();
        tmp[t] += u;
        __syncthreads();
    }
    pexcl[(long)t * NBUCK + b] = tmp[t] - v;
    if (t == 255) total[b] = tmp[255];
}

// scan bucket totals -> bucket_base[NBUCK+1] (edge offsets; == CSR base per bucket)
__global__ __launch_bounds__(256) void k2b(const int* __restrict__ total,
                                           int* __restrict__ bucket_base) {
    __shared__ int tmp[256];
    int t = threadIdx.x;
    int v = (t < NBUCK) ? total[t] : 0;
    tmp[t] = v;
    __syncthreads();
    for (int off = 1; off < 256; off <<= 1) {
        int u = (t >= off) ? tmp[t - off] : 0;
        __syncthreads();
        tmp[t] += u;
        __syncthreads();
    }
    if (t < NBUCK) bucket_base[t] = tmp[t] - v;
    if (t == 255) bucket_base[NBUCK] = tmp[255];
}

// pass 2: scatter packed (src<<9 | dst&511) into bucket-grouped bstore
__global__ __launch_bounds__(256) void k3_scatter(const int* __restrict__ ei,
                                                  const int* __restrict__ flags,
                                                  const int* __restrict__ pexcl,
                                                  const int* __restrict__ bucket_base,
                                                  uint* __restrict__ bstore) {
    __shared__ int pos[NBUCK];
    int tid = threadIdx.x;
    for (int i = tid; i < NBUCK; i += 256)
        pos[i] = bucket_base[i] + pexcl[(long)blockIdx.x * NBUCK + i];
    __syncthreads();
    int i64 = flags[1];
    for (int e = blockIdx.x * 256 + tid; e < N_EDGES; e += NB1 * 256) {
        int r = geti(ei, e, i64);
        int c = geti(ei, (long)N_EDGES + e, i64);
        int p = atomicAdd(&pos[c >> BSH], 1);
        bstore[p] = ((uint)r << BSH) | (uint)(c & 511);
    }
}

// per bucket: degree histogram + LDS scan -> deg/dinv/row_end, scatter csr_src
// (all csr writes stay inside the bucket's contiguous ~32KB region)
__global__ __launch_bounds__(256) void k4_csr(const uint* __restrict__ bstore,
                                              const int* __restrict__ bucket_base,
                                              int* __restrict__ deg,
                                              float* __restrict__ dinv,
                                              int* __restrict__ row_end,
                                              int* __restrict__ csr_src) {
    __shared__ int cnt[512];
    __shared__ int exc[512];
    __shared__ int tmp[256];
    int b = blockIdx.x, t = threadIdx.x;
    cnt[t] = 0; cnt[t + 256] = 0;
    __syncthreads();
    int bb = bucket_base[b];
    int m = bucket_base[b + 1] - bb;
    const uint* bs = bstore + bb;
    for (int i = t; i < m; i += 256) atomicAdd(&cnt[bs[i] & 511], 1);
    __syncthreads();
    int c0 = cnt[2 * t], c1 = cnt[2 * t + 1];
    tmp[t] = c0 + c1;
    __syncthreads();
    for (int off = 1; off < 256; off <<= 1) {
        int u = (t >= off) ? tmp[t - off] : 0;
        __syncthreads();
        tmp[t] += u;
        __syncthreads();
    }
    int ep = tmp[t] - (c0 + c1);
    exc[2 * t] = ep;
    exc[2 * t + 1] = ep + c0;
    int n0 = (b << BSH) + 2 * t;
    if (n0 < N_NODES) {
        deg[n0] = c0;
        dinv[n0] = rsqrtf((float)c0 + 1.0f);
        row_end[n0] = bb + ep + c0;
    }
    if (n0 + 1 < N_NODES) {
        deg[n0 + 1] = c1;
        dinv[n0 + 1] = rsqrtf((float)c1 + 1.0f);
        row_end[n0 + 1] = bb + ep + c0 + c1;
    }
    __syncthreads();
    for (int i = t; i < m; i += 256) {
        uint p = bs[i];
        int pos = atomicAdd(&exc[p & 511], 1);
        csr_src[bb + pos] = (int)(p >> BSH);
    }
}

// ---------------- MFMA node-linear ----------------
template <int K, int KA, int AMODE, int BIAS, int ACT, int SCALE, int OUTF32>
__global__ __launch_bounds__(256) void k_mm(const void* __restrict__ A0,
                                            const void* __restrict__ A1,
                                            const void* __restrict__ W,
                                            const void* __restrict__ Bv,
                                            const float* __restrict__ dinv,
                                            const int* __restrict__ flags,
                                            long w_off, long b_off,
                                            void* __restrict__ outp,
                                            long orow, long ooff) {
    __shared__ short wT[64 * (K + 8)];
    __shared__ float bl[64];
    const int isf32 = flags[0];
    const int tid = threadIdx.x;
    for (int i = tid; i < 64 * K; i += 256) {
        int k = i >> 6, f = i & 63;          // coalesced W read order
        float v = (k < KA) ? ldf(W, w_off + i, isf32) : 0.f;
        bf16 h = f2b(v);
        wT[f * (K + 8) + k] = *(short*)&h;
    }
    if (BIAS && tid < 64) bl[tid] = ldf(Bv, b_off + tid, isf32);
    __syncthreads();

    const int lane = tid & 63, wv = tid >> 6;
    const int m = lane & 15, quad = lane >> 4;

    short8 bfr[4][K / 32];
    #pragma unroll
    for (int cb = 0; cb < 4; cb++)
        #pragma unroll
        for (int ks = 0; ks < K / 32; ks++)
            bfr[cb][ks] = *(const short8*)&wT[(cb * 16 + m) * (K + 8) + ks * 32 + quad * 8];

    for (int t = blockIdx.x * 4 + wv; t < NTILES; t += gridDim.x * 4) {
        const int n0 = t * 16;
        short8 af[K / 32];
        if constexpr (AMODE == 0) {
            const bf16* Ab = (const bf16*)A0;
            #pragma unroll
            for (int ks = 0; ks < K / 32; ks++)
                af[ks] = *(const short8*)&Ab[(long)(n0 + m) * K + ks * 32 + quad * 8];
        } else if constexpr (AMODE == 2) {
            const bf16* Xb = (const bf16*)A0;
            const bf16* Sb = (const bf16*)A1;
            #pragma unroll
            for (int ks = 0; ks < 4; ks++) {
                const bf16* base = (ks < 2) ? &Xb[(long)(n0 + m) * 64 + ks * 32]
                                            : &Sb[(long)(n0 + m) * 64 + (ks - 2) * 32];
                af[ks] = *(const short8*)&base[quad * 8];
            }
        } else {
            if (isf32) {
                const float* Af = (const float*)A0 + (long)(n0 + m) * KA;
                #pragma unroll
                for (int ks = 0; ks < K / 32; ks++) {
                    short8 a;
                    #pragma unroll
                    for (int j = 0; j < 8; j++) {
                        int k = ks * 32 + quad * 8 + j;
                        float v = (KA % 32 == 0 || k < KA) ? Af[k] : 0.f;
                        bf16 h = f2b(v);
                        a[j] = *(short*)&h;
                    }
                    af[ks] = a;
                }
            } else {
                const bf16* Ab = (const bf16*)A0 + (long)(n0 + m) * KA;
                #pragma unroll
                for (int ks = 0; ks < K / 32; ks++) {
                    if constexpr (KA % 32 == 0) {
                        af[ks] = *(const short8*)&Ab[ks * 32 + quad * 8];
                    } else {
                        short8 a;
                        #pragma unroll
                        for (int j = 0; j < 8; j++) {
                            int k = ks * 32 + quad * 8 + j;
                            float v = (k < KA) ? b2f(Ab[k]) : 0.f;
                            bf16 h = f2b(v);
                            a[j] = *(short*)&h;
                        }
                        af[ks] = a;
                    }
                }
            }
        }
        float4v c[4];
        #pragma unroll
        for (int cb = 0; cb < 4; cb++) { c[cb][0] = 0.f; c[cb][1] = 0.f; c[cb][2] = 0.f; c[cb][3] = 0.f; }
        #pragma unroll
        for (int ks = 0; ks < K / 32; ks++)
            #pragma unroll
            for (int cb = 0; cb < 4; cb++)
                c[cb] = __builtin_amdgcn_mfma_f32_16x16x32_bf16(af[ks], bfr[cb][ks], c[cb], 0, 0, 0);
        #pragma unroll
        for (int cb = 0; cb < 4; cb++) {
            int feat = cb * 16 + m;
            float bb = BIAS ? bl[feat] : 0.f;
            #pragma unroll
            for (int r = 0; r < 4; r++) {
                int n = n0 + quad * 4 + r;
                float v = c[cb][r] + bb;
                if (SCALE) v *= dinv[n];
                if (ACT) v = fmaxf(v, 0.f);
                if (OUTF32) ((float*)outp)[(long)n * orow + ooff + feat] = v;
                else ((bf16*)outp)[(long)n * orow + ooff + feat] = f2b(v);
            }
        }
    }
}

// ---------------- fused GIN+GCN gather ----------------
__global__ __launch_bounds__(256) void k_gather2(const uint* __restrict__ zsw,
                                                 const int* __restrict__ row_end,
                                                 const int* __restrict__ deg,
                                                 const int* __restrict__ csr_src,
                                                 const void* __restrict__ b1,
                                                 const void* __restrict__ bg,
                                                 const float* __restrict__ dinv,
                                                 const int* __restrict__ flags,
                                                 long b_off,
                                                 uint* __restrict__ hB,
                                                 uint* __restrict__ sOut) {
    int tid = threadIdx.x;
    int wv = tid >> 6, lane = tid & 63;
    int half = lane >> 5, fl = lane & 31;
    int isf32 = flags[0];
    float bb0, bb1;
    if (half == 0) {
        bb0 = ldf(b1, b_off + 2 * fl, isf32);
        bb1 = ldf(b1, b_off + 2 * fl + 1, isf32);
    } else {
        bb0 = ldf(bg, b_off + 2 * fl, isf32);
        bb1 = ldf(bg, b_off + 2 * fl + 1, isf32);
    }
    int n = blockIdx.x * 4 + wv;
    if (n >= N_NODES) return;
    int end = row_end[n], beg = end - deg[n];
    uint u = zsw[(long)n * 64 + lane];
    float a0 = bflo(u), a1 = bfhi(u);
    int p = beg;
    for (; p + 8 <= end; p += 8) {
        int i0 = csr_src[p], i1 = csr_src[p + 1], i2 = csr_src[p + 2], i3 = csr_src[p + 3];
        int i4 = csr_src[p + 4], i5 = csr_src[p + 5], i6 = csr_src[p + 6], i7 = csr_src[p + 7];
        uint u0 = zsw[(long)i0 * 64 + lane], u1 = zsw[(long)i1 * 64 + lane];
        uint u2 = zsw[(long)i2 * 64 + lane], u3 = zsw[(long)i3 * 64 + lane];
        uint u4 = zsw[(long)i4 * 64 + lane], u5 = zsw[(long)i5 * 64 + lane];
        uint u6 = zsw[(long)i6 * 64 + lane], u7 = zsw[(long)i7 * 64 + lane];
        a0 += ((bflo(u0) + bflo(u1)) + (bflo(u2) + bflo(u3)))
            + ((bflo(u4) + bflo(u5)) + (bflo(u6) + bflo(u7)));
        a1 += ((bfhi(u0) + bfhi(u1)) + (bfhi(u2) + bfhi(u3)))
            + ((bfhi(u4) + bfhi(u5)) + (bfhi(u6) + bfhi(u7)));
    }
    for (; p < end; p++) {
        uint uu = zsw[(long)csr_src[p] * 64 + lane];
        a0 += bflo(uu); a1 += bfhi(uu);
    }
    if (half == 0) {
        hB[(long)n * 32 + fl] = packbf(fmaxf(a0 + bb0, 0.f), fmaxf(a1 + bb1, 0.f));
    } else {
        float dn = dinv[n];
        sOut[(long)n * 32 + fl] = packbf(tanhf(dn * a0 + bb0), tanhf(dn * a1 + bb1));
    }
}

// ---------------- pool: run-length segmented sum over sorted batch ----------------
__global__ __launch_bounds__(256) void k_pool(const float* __restrict__ xw,
                                              const int* __restrict__ batch,
                                              const int* __restrict__ flags,
                                              float* __restrict__ xp) {
    int tid = threadIdx.x;
    int slot = tid >> 6, lane = tid & 63;
    int nbeg = (blockIdx.x * 4 + slot) * 16;
    if (nbeg >= N_NODES) return;
    int nend = nbeg + 16;
    if (nend > N_NODES) nend = N_NODES;
    int i64 = flags[1];
    int g = geti(batch, nbeg, i64);
    float acc = 0.f;
    for (int n = nbeg; n < nend; n++) {
        int gn = geti(batch, n, i64);
        if (gn != g) { atomicAdd(&xp[(long)g * 64 + lane], acc); acc = 0.f; g = gn; }
        acc += xw[(long)n * 64 + lane];
    }
    atomicAdd(&xp[(long)g * 64 + lane], acc);
}

// ---------------- final: post + readout + log_softmax ----------------
__global__ __launch_bounds__(64) void k_final(const float* __restrict__ xp,
                                              const void* __restrict__ post_w,
                                              const void* __restrict__ post_b,
                                              const void* __restrict__ ro_w,
                                              const void* __restrict__ ro_b,
                                              const int* __restrict__ flags,
                                              void* __restrict__ out) {
    __shared__ float h2[64];
    __shared__ float lg[16];
    int isf32 = flags[0];
    int g = blockIdx.x;
    int f = threadIdx.x;
    float xr = xp[(long)g * 64 + f];
    float acc = ldf(post_b, f, isf32);
    #pragma unroll
    for (int j = 0; j < 64; j++) acc += __shfl(xr, j) * ldf(post_w, j * 64 + f, isf32);
    float v = fmaxf(acc, 0.f);
    h2[f] = v;
    long oxp = (long)g * 64 + f;
    if (isf32) ((float*)out)[oxp] = v; else ((bf16*)out)[oxp] = f2b(v);
    __syncthreads();
    if (f < 16) {
        float a = ldf(ro_b, f, isf32);
        for (int j = 0; j < 64; j++) a += h2[j] * ldf(ro_w, j * 16 + f, isf32);
        lg[f] = a;
    }
    __syncthreads();
    if (f < 16) {
        float m = -1e30f;
        for (int j = 0; j < 16; j++) m = fmaxf(m, lg[j]);
        float sum = 0.f;
        for (int j = 0; j < 16; j++) sum += expf(lg[j] - m);
        long oy = (long)N_GRAPHS * 64 + (long)g * 16 + f;
        float yv = lg[f] - m - logf(sum);
        if (isf32) ((float*)out)[oy] = yv; else ((bf16*)out)[oy] = f2b(yv);
    }
}

extern "C" void kernel_launch(void* const* d_in, const int* in_sizes, int n_in,
                              void* d_out, int out_size, void* d_ws, size_t ws_size,
                              hipStream_t stream) {
    const void* x_in  = d_in[0];
    const void* s_in  = d_in[1];
    const int*  ei    = (const int*)d_in[2];
    const int*  batch = (const int*)d_in[3];
    const void* pre_w = d_in[4];
    const void* pre_b = d_in[5];
    const void* emb_w = d_in[6];
    const void* emb_b = d_in[7];
    const void* gin_w1 = d_in[8];
    const void* gin_b1 = d_in[9];
    const void* gin_w2 = d_in[10];
    const void* gin_b2 = d_in[11];
    const void* gcn_w  = d_in[12];
    const void* gcn_b  = d_in[13];
    const void* whp_w  = d_in[14];
    const void* whp_b  = d_in[15];
    const void* post_w = d_in[16];
    const void* post_b = d_in[17];
    const void* ro_w   = d_in[18];
    const void* ro_b   = d_in[19];

    // ws: flags(64) | deg(N) | row_end(N) | hist(NB1*NBUCK) | pexcl(NB1*NBUCK)
    //   | total(NBUCK) | bucket_base(NBUCK+1+pad) | bstore(E) | csr_src(E) | dinv(N)
    //   | x0,x1,sA,hB (bf16 N*64) | zsw (uint N*64) | wout (f32 N*64) | xp
    int* flags   = (int*)d_ws;
    int* deg     = flags + 64;
    int* row_end = deg + N_NODES;
    int* hist    = row_end + N_NODES;
    int* pexcl   = hist + NB1 * NBUCK;
    int* total   = pexcl + NB1 * NBUCK;
    int* bbase   = total + NBUCK;
    uint* bstore = (uint*)(bbase + NBUCK + 4);
    int* csr_src = (int*)(bstore + N_EDGES);
    float* dinv  = (float*)(csr_src + N_EDGES);
    bf16* x0     = (bf16*)(dinv + N_NODES);
    bf16* x1     = x0 + (long)N_NODES * 64;
    bf16* sA     = x1 + (long)N_NODES * 64;
    bf16* hB     = sA + (long)N_NODES * 64;
    uint* zsw    = (uint*)(hB + (long)N_NODES * 64);
    float* wout  = (float*)(zsw + (long)N_NODES * 64);
    float* xp    = wout + (long)N_NODES * 64;

    const int MMB = 512;
    const int GGB = (N_NODES + 3) / 4;       // 25000

    k_detect<<<1, 64, 0, stream>>>(x_in, ei, flags);

    // CSR + deg + dinv + row_end: two-pass radix partition
    k1_hist<<<NB1, 256, 0, stream>>>(ei, flags, hist);
    k2a<<<NBUCK, 256, 0, stream>>>(hist, pexcl, total);
    k2b<<<1, 256, 0, stream>>>(total, bbase);
    k3_scatter<<<NB1, 256, 0, stream>>>(ei, flags, pexcl, bbase, bstore);
    k4_csr<<<NBUCK, 256, 0, stream>>>(bstore, bbase, deg, dinv, row_end, csr_src);

    const long W1 = 128 * 64, W2 = 64 * 64, WG = 64 * 64, B = 64;

    // pre / embedding -> bf16 activations
    k_mm<128, 128, 1, 1, 0, 0, 0><<<MMB, 256, 0, stream>>>(x_in, nullptr, pre_w, pre_b, dinv, flags, 0L, 0L, x0, 64, 0);
    k_mm<32, 16, 1, 1, 0, 0, 0><<<MMB, 256, 0, stream>>>(s_in, nullptr, emb_w, emb_b, dinv, flags, 0L, 0L, sA, 64, 0);

    // ---- layer 0: x0 -> x1 ----
    k_mm<128, 128, 2, 0, 0, 0, 0><<<MMB, 256, 0, stream>>>(x0, sA, gin_w1, nullptr, dinv, flags, 0L, 0L, zsw, 128, 0);
    k_mm<64, 64, 0, 0, 0, 1, 0><<<MMB, 256, 0, stream>>>(sA, nullptr, gcn_w, nullptr, dinv, flags, 0L, 0L, zsw, 128, 64);
    k_gather2<<<GGB, 256, 0, stream>>>(zsw, row_end, deg, csr_src, gin_b1, gcn_b, dinv, flags, 0L, (uint*)hB, (uint*)sA);
    k_mm<64, 64, 0, 1, 1, 0, 0><<<MMB, 256, 0, stream>>>(hB, nullptr, gin_w2, gin_b2, dinv, flags, 0L, 0L, x1, 64, 0);

    // ---- layer 1: x1 -> x0 ----
    k_mm<128, 128, 2, 0, 0, 0, 0><<<MMB, 256, 0, stream>>>(x1, sA, gin_w1, nullptr, dinv, flags, W1, 0L, zsw, 128, 0);
    k_mm<64, 64, 0, 0, 0, 1, 0><<<MMB, 256, 0, stream>>>(sA, nullptr, gcn_w, nullptr, dinv, flags, WG, 0L, zsw, 128, 64);
    k_gather2<<<GGB, 256, 0, stream>>>(zsw, row_end, deg, csr_src, gin_b1, gcn_b, dinv, flags, B, (uint*)hB, (uint*)sA);
    k_mm<64, 64, 0, 1, 1, 0, 0><<<MMB, 256, 0, stream>>>(hB, nullptr, gin_w2, gin_b2, dinv, flags, W2, B, x0, 64, 0);

    // ---- head ----
    k_mm<128, 128, 2, 1, 0, 0, 1><<<MMB, 256, 0, stream>>>(x0, sA, whp_w, whp_b, dinv, flags, 0L, 0L, wout, 64, 0);
    hipMemsetAsync(xp, 0, (size_t)N_GRAPHS * 64 * sizeof(float), stream);
    k_pool<<<(N_NODES + 63) / 64, 256, 0, stream>>>(wout, batch, flags, xp);

    k_final<<<N_GRAPHS, 64, 0, stream>>>(xp, post_w, post_b, ro_w, ro_b, flags, d_out);
}

// Round 9
// 540.014 us; speedup vs baseline: 2.5966x; 1.0231x over previous
//
#include <hip/hip_runtime.h>
#include <hip/hip_bf16.h>

#define N_NODES 100000
#define N_EDGES 1600000
#define N_GRAPHS 512
#define NTILES (N_NODES / 16)          // 6250, exact
#define BSH 9                          // 512 nodes per bucket
#define NBUCK ((N_NODES + 511) >> BSH) // 196
#define NB1 256                        // blocks for hist/scatter passes

typedef __hip_bfloat16 bf16;
typedef unsigned int uint;
typedef unsigned short ushort;
typedef __attribute__((ext_vector_type(8))) short short8;
typedef __attribute__((ext_vector_type(4))) float float4v;

__device__ __forceinline__ float b2f(bf16 v) { return __bfloat162float(v); }
__device__ __forceinline__ bf16 f2b(float v) { return __float2bfloat16(v); }
__device__ __forceinline__ short f2bs(float v) { bf16 h = f2b(v); return *(short*)&h; }

__device__ __forceinline__ float ldf(const void* p, long i, int isf32) {
    return isf32 ? ((const float*)p)[i] : b2f(((const bf16*)p)[i]);
}
__device__ __forceinline__ int geti(const int* p, long i, int is64) {
    return is64 ? p[2 * i] : p[i];
}
__device__ __forceinline__ float bflo(uint u) { return __uint_as_float(u << 16); }
__device__ __forceinline__ float bfhi(uint u) { return __uint_as_float(u & 0xffff0000u); }
__device__ __forceinline__ uint packbf(float x, float y) {
    bf16 a = f2b(x), b = f2b(y);
    ushort ua = *(ushort*)&a, ub = *(ushort*)&b;
    return (uint)ua | ((uint)ub << 16);
}

// ---------------- dtype detection ----------------
__global__ void k_detect(const void* __restrict__ x, const int* __restrict__ ei,
                         int* __restrict__ flags) {
    if (threadIdx.x != 0 || blockIdx.x != 0) return;
    const ushort* xu = (const ushort*)x;
    int plaus = 0;
    for (int i = 0; i < 256; i++) {
        ushort u = xu[2 * i];
        int e = (u >> 7) & 0xFF;
        if (u == 0 || (e >= 116 && e <= 132)) plaus++;
    }
    flags[0] = (plaus < 128) ? 1 : 0;          // 1 => fp32 inputs
    int nz = 0;
    for (int i = 0; i < 128; i++) if (ei[2 * i + 1] != 0) nz++;
    flags[1] = (nz < 8) ? 1 : 0;               // 1 => int64 indices
}

// ---------------- CSR build: deterministic 2-pass radix partition ----------------
__global__ __launch_bounds__(256) void k1_hist(const int* __restrict__ ei,
                                               const int* __restrict__ flags,
                                               int* __restrict__ hist) {
    __shared__ int h[NBUCK];
    int tid = threadIdx.x;
    for (int i = tid; i < NBUCK; i += 256) h[i] = 0;
    __syncthreads();
    int i64 = flags[1];
    for (int e = blockIdx.x * 256 + tid; e < N_EDGES; e += NB1 * 256) {
        int c = geti(ei, (long)N_EDGES + e, i64);
        atomicAdd(&h[c >> BSH], 1);
    }
    __syncthreads();
    for (int i = tid; i < NBUCK; i += 256) hist[(long)blockIdx.x * NBUCK + i] = h[i];
}

__global__ __launch_bounds__(256) void k2a(const int* __restrict__ hist,
                                           int* __restrict__ pexcl,
                                           int* __restrict__ total) {
    __shared__ int tmp[256];
    int b = blockIdx.x, t = threadIdx.x;
    int v = hist[(long)t * NBUCK + b];
    tmp[t] = v;
    __syncthreads();
    for (int off = 1; off < 256; off <<= 1) {
        int u = (t >= off) ? tmp[t - off] : 0;
        __syncthreads();
        tmp[t] += u;
        __syncthreads();
    }
    pexcl[(long)t * NBUCK + b] = tmp[t] - v;
    if (t == 255) total[b] = tmp[255];
}

__global__ __launch_bounds__(256) void k2b(const int* __restrict__ total,
                                           int* __restrict__ bucket_base) {
    __shared__ int tmp[256];
    int t = threadIdx.x;
    int v = (t < NBUCK) ? total[t] : 0;
    tmp[t] = v;
    __syncthreads();
    for (int off = 1; off < 256; off <<= 1) {
        int u = (t >= off) ? tmp[t - off] : 0;
        __syncthreads();
        tmp[t] += u;
        __syncthreads();
    }
    if (t < NBUCK) bucket_base[t] = tmp[t] - v;
    if (t == 255) bucket_base[NBUCK] = tmp[255];
}

__global__ __launch_bounds__(256) void k3_scatter(const int* __restrict__ ei,
                                                  const int* __restrict__ flags,
                                                  const int* __restrict__ pexcl,
                                                  const int* __restrict__ bucket_base,
                                                  uint* __restrict__ bstore) {
    __shared__ int pos[NBUCK];
    int tid = threadIdx.x;
    for (int i = tid; i < NBUCK; i += 256)
        pos[i] = bucket_base[i] + pexcl[(long)blockIdx.x * NBUCK + i];
    __syncthreads();
    int i64 = flags[1];
    for (int e = blockIdx.x * 256 + tid; e < N_EDGES; e += NB1 * 256) {
        int r = geti(ei, e, i64);
        int c = geti(ei, (long)N_EDGES + e, i64);
        int p = atomicAdd(&pos[c >> BSH], 1);
        bstore[p] = ((uint)r << BSH) | (uint)(c & 511);
    }
}

__global__ __launch_bounds__(256) void k4_csr(const uint* __restrict__ bstore,
                                              const int* __restrict__ bucket_base,
                                              int* __restrict__ deg,
                                              float* __restrict__ dinv,
                                              int* __restrict__ row_end,
                                              int* __restrict__ csr_src) {
    __shared__ int cnt[512];
    __shared__ int exc[512];
    __shared__ int tmp[256];
    int b = blockIdx.x, t = threadIdx.x;
    cnt[t] = 0; cnt[t + 256] = 0;
    __syncthreads();
    int bb = bucket_base[b];
    int m = bucket_base[b + 1] - bb;
    const uint* bs = bstore + bb;
    for (int i = t; i < m; i += 256) atomicAdd(&cnt[bs[i] & 511], 1);
    __syncthreads();
    int c0 = cnt[2 * t], c1 = cnt[2 * t + 1];
    tmp[t] = c0 + c1;
    __syncthreads();
    for (int off = 1; off < 256; off <<= 1) {
        int u = (t >= off) ? tmp[t - off] : 0;
        __syncthreads();
        tmp[t] += u;
        __syncthreads();
    }
    int ep = tmp[t] - (c0 + c1);
    exc[2 * t] = ep;
    exc[2 * t + 1] = ep + c0;
    int n0 = (b << BSH) + 2 * t;
    if (n0 < N_NODES) {
        deg[n0] = c0;
        dinv[n0] = rsqrtf((float)c0 + 1.0f);
        row_end[n0] = bb + ep + c0;
    }
    if (n0 + 1 < N_NODES) {
        deg[n0 + 1] = c1;
        dinv[n0 + 1] = rsqrtf((float)c1 + 1.0f);
        row_end[n0 + 1] = bb + ep + c0 + c1;
    }
    __syncthreads();
    for (int i = t; i < m; i += 256) {
        uint p = bs[i];
        int pos = atomicAdd(&exc[p & 511], 1);
        csr_src[bb + pos] = (int)(p >> BSH);
    }
}

// ---------------- MFMA input linear (pre / emb) ----------------
template <int K, int KA>
__global__ __launch_bounds__(256) void k_mm_in(const void* __restrict__ A0,
                                               const void* __restrict__ W,
                                               const void* __restrict__ Bv,
                                               const int* __restrict__ flags,
                                               bf16* __restrict__ outp) {
    __shared__ short wT[64 * (K + 8)];
    __shared__ float bl[64];
    const int isf32 = flags[0];
    const int tid = threadIdx.x;
    for (int i = tid; i < 64 * K; i += 256) {
        int k = i >> 6, f = i & 63;
        float v = (k < KA) ? ldf(W, i, isf32) : 0.f;
        wT[f * (K + 8) + k] = f2bs(v);
    }
    if (tid < 64) bl[tid] = ldf(Bv, tid, isf32);
    __syncthreads();

    const int lane = tid & 63, wv = tid >> 6;
    const int m = lane & 15, quad = lane >> 4;

    short8 bfr[4][K / 32];
    #pragma unroll
    for (int cb = 0; cb < 4; cb++)
        #pragma unroll
        for (int ks = 0; ks < K / 32; ks++)
            bfr[cb][ks] = *(const short8*)&wT[(cb * 16 + m) * (K + 8) + ks * 32 + quad * 8];

    for (int t = blockIdx.x * 4 + wv; t < NTILES; t += gridDim.x * 4) {
        const int n0 = t * 16;
        short8 af[K / 32];
        if (isf32) {
            const float* Af = (const float*)A0 + (long)(n0 + m) * KA;
            #pragma unroll
            for (int ks = 0; ks < K / 32; ks++) {
                short8 a;
                #pragma unroll
                for (int j = 0; j < 8; j++) {
                    int k = ks * 32 + quad * 8 + j;
                    float v = (KA % 32 == 0 || k < KA) ? Af[k] : 0.f;
                    a[j] = f2bs(v);
                }
                af[ks] = a;
            }
        } else {
            const bf16* Ab = (const bf16*)A0 + (long)(n0 + m) * KA;
            #pragma unroll
            for (int ks = 0; ks < K / 32; ks++) {
                if constexpr (KA % 32 == 0) {
                    af[ks] = *(const short8*)&Ab[ks * 32 + quad * 8];
                } else {
                    short8 a;
                    #pragma unroll
                    for (int j = 0; j < 8; j++) {
                        int k = ks * 32 + quad * 8 + j;
                        float v = (k < KA) ? b2f(Ab[k]) : 0.f;
                        a[j] = f2bs(v);
                    }
                    af[ks] = a;
                }
            }
        }
        float4v c[4];
        #pragma unroll
        for (int cb = 0; cb < 4; cb++) { c[cb][0]=0.f; c[cb][1]=0.f; c[cb][2]=0.f; c[cb][3]=0.f; }
        #pragma unroll
        for (int ks = 0; ks < K / 32; ks++)
            #pragma unroll
            for (int cb = 0; cb < 4; cb++)
                c[cb] = __builtin_amdgcn_mfma_f32_16x16x32_bf16(af[ks], bfr[cb][ks], c[cb], 0, 0, 0);
        #pragma unroll
        for (int cb = 0; cb < 4; cb++) {
            int feat = cb * 16 + m;
            #pragma unroll
            for (int r = 0; r < 4; r++) {
                int n = n0 + quad * 4 + r;
                outp[(long)n * 64 + feat] = f2b(c[cb][r] + bl[feat]);
            }
        }
    }
}

// ---------------- mmA: zsw[n][0:64]=[x,s]@W1 ; zsw[n][64:128]=dinv*(s@Wg) ----------------
__global__ __launch_bounds__(256) void k_mmA(const bf16* __restrict__ x,
                                             const bf16* __restrict__ s,
                                             const void* __restrict__ W1,
                                             const void* __restrict__ Wg,
                                             const float* __restrict__ dinv,
                                             const int* __restrict__ flags,
                                             long w1_off, long wg_off,
                                             bf16* __restrict__ zsw) {
    __shared__ short wT1[64 * 136];
    __shared__ short wTg[64 * 72];
    const int isf32 = flags[0];
    const int tid = threadIdx.x;
    for (int i = tid; i < 64 * 128; i += 256) {
        int k = i >> 6, f = i & 63;
        wT1[f * 136 + k] = f2bs(ldf(W1, w1_off + i, isf32));
    }
    for (int i = tid; i < 64 * 64; i += 256) {
        int k = i >> 6, f = i & 63;
        wTg[f * 72 + k] = f2bs(ldf(Wg, wg_off + i, isf32));
    }
    __syncthreads();

    const int lane = tid & 63, wv = tid >> 6;
    const int m = lane & 15, quad = lane >> 4;

    short8 w1f[4][4], wgf[4][2];
    #pragma unroll
    for (int cb = 0; cb < 4; cb++) {
        #pragma unroll
        for (int ks = 0; ks < 4; ks++)
            w1f[cb][ks] = *(const short8*)&wT1[(cb * 16 + m) * 136 + ks * 32 + quad * 8];
        #pragma unroll
        for (int ks = 0; ks < 2; ks++)
            wgf[cb][ks] = *(const short8*)&wTg[(cb * 16 + m) * 72 + ks * 32 + quad * 8];
    }

    for (int t = blockIdx.x * 4 + wv; t < NTILES; t += gridDim.x * 4) {
        const int n0 = t * 16;
        short8 a[4];
        a[0] = *(const short8*)&x[(long)(n0 + m) * 64 + quad * 8];
        a[1] = *(const short8*)&x[(long)(n0 + m) * 64 + 32 + quad * 8];
        a[2] = *(const short8*)&s[(long)(n0 + m) * 64 + quad * 8];
        a[3] = *(const short8*)&s[(long)(n0 + m) * 64 + 32 + quad * 8];
        float4v cz[4], cd[4];
        #pragma unroll
        for (int cb = 0; cb < 4; cb++) {
            cz[cb][0]=0.f; cz[cb][1]=0.f; cz[cb][2]=0.f; cz[cb][3]=0.f;
            cd[cb][0]=0.f; cd[cb][1]=0.f; cd[cb][2]=0.f; cd[cb][3]=0.f;
        }
        #pragma unroll
        for (int ks = 0; ks < 4; ks++)
            #pragma unroll
            for (int cb = 0; cb < 4; cb++)
                cz[cb] = __builtin_amdgcn_mfma_f32_16x16x32_bf16(a[ks], w1f[cb][ks], cz[cb], 0, 0, 0);
        #pragma unroll
        for (int ks = 0; ks < 2; ks++)
            #pragma unroll
            for (int cb = 0; cb < 4; cb++)
                cd[cb] = __builtin_amdgcn_mfma_f32_16x16x32_bf16(a[2 + ks], wgf[cb][ks], cd[cb], 0, 0, 0);
        #pragma unroll
        for (int cb = 0; cb < 4; cb++) {
            int feat = cb * 16 + m;
            #pragma unroll
            for (int r = 0; r < 4; r++) {
                int n = n0 + quad * 4 + r;
                zsw[(long)n * 128 + feat] = f2b(cz[cb][r]);
                zsw[(long)n * 128 + 64 + feat] = f2b(cd[cb][r] * dinv[n]);
            }
        }
    }
}

// ---------------- mmB: x'=relu(hB@W2+b2) [LDS only]; zsw=[x',s]@W1n | dinv*(s@Wgn) ----------------
__global__ __launch_bounds__(256) void k_mmB(const bf16* __restrict__ hB,
                                             const bf16* __restrict__ s,
                                             const void* __restrict__ W2,
                                             const void* __restrict__ B2,
                                             const void* __restrict__ W1n,
                                             const void* __restrict__ Wgn,
                                             const float* __restrict__ dinv,
                                             const int* __restrict__ flags,
                                             long w2_off, long b2_off, long w1n_off, long wgn_off,
                                             bf16* __restrict__ zsw) {
    __shared__ short wT2[64 * 72];
    __shared__ short wT1[64 * 136];
    __shared__ short wTg[64 * 72];
    __shared__ float bl2[64];
    __shared__ short xbuf[4][16 * 72];
    const int isf32 = flags[0];
    const int tid = threadIdx.x;
    for (int i = tid; i < 64 * 64; i += 256) {
        int k = i >> 6, f = i & 63;
        wT2[f * 72 + k] = f2bs(ldf(W2, w2_off + i, isf32));
        wTg[f * 72 + k] = f2bs(ldf(Wgn, wgn_off + i, isf32));
    }
    for (int i = tid; i < 64 * 128; i += 256) {
        int k = i >> 6, f = i & 63;
        wT1[f * 136 + k] = f2bs(ldf(W1n, w1n_off + i, isf32));
    }
    if (tid < 64) bl2[tid] = ldf(B2, b2_off + tid, isf32);
    __syncthreads();

    const int lane = tid & 63, wv = tid >> 6;
    const int m = lane & 15, quad = lane >> 4;

    short8 w2f[4][2], w1f[4][4];
    #pragma unroll
    for (int cb = 0; cb < 4; cb++) {
        #pragma unroll
        for (int ks = 0; ks < 2; ks++)
            w2f[cb][ks] = *(const short8*)&wT2[(cb * 16 + m) * 72 + ks * 32 + quad * 8];
        #pragma unroll
        for (int ks = 0; ks < 4; ks++)
            w1f[cb][ks] = *(const short8*)&wT1[(cb * 16 + m) * 136 + ks * 32 + quad * 8];
    }

    for (int base = blockIdx.x * 4; base < NTILES; base += gridDim.x * 4) {
        int t = base + wv;
        bool valid = (t < NTILES);
        int n0 = t * 16;
        if (valid) {
            short8 ah[2];
            ah[0] = *(const short8*)&hB[(long)(n0 + m) * 64 + quad * 8];
            ah[1] = *(const short8*)&hB[(long)(n0 + m) * 64 + 32 + quad * 8];
            float4v cx[4];
            #pragma unroll
            for (int cb = 0; cb < 4; cb++) { cx[cb][0]=0.f; cx[cb][1]=0.f; cx[cb][2]=0.f; cx[cb][3]=0.f; }
            #pragma unroll
            for (int ks = 0; ks < 2; ks++)
                #pragma unroll
                for (int cb = 0; cb < 4; cb++)
                    cx[cb] = __builtin_amdgcn_mfma_f32_16x16x32_bf16(ah[ks], w2f[cb][ks], cx[cb], 0, 0, 0);
            #pragma unroll
            for (int cb = 0; cb < 4; cb++) {
                int feat = cb * 16 + m;
                float bb = bl2[feat];
                #pragma unroll
                for (int r = 0; r < 4; r++)
                    xbuf[wv][(quad * 4 + r) * 72 + feat] = f2bs(fmaxf(cx[cb][r] + bb, 0.f));
            }
        }
        __syncthreads();
        if (valid) {
            short8 a[4];
            a[0] = *(const short8*)&xbuf[wv][m * 72 + quad * 8];
            a[1] = *(const short8*)&xbuf[wv][m * 72 + 32 + quad * 8];
            a[2] = *(const short8*)&s[(long)(n0 + m) * 64 + quad * 8];
            a[3] = *(const short8*)&s[(long)(n0 + m) * 64 + 32 + quad * 8];
            float4v cz[4], cd[4];
            #pragma unroll
            for (int cb = 0; cb < 4; cb++) {
                cz[cb][0]=0.f; cz[cb][1]=0.f; cz[cb][2]=0.f; cz[cb][3]=0.f;
                cd[cb][0]=0.f; cd[cb][1]=0.f; cd[cb][2]=0.f; cd[cb][3]=0.f;
            }
            #pragma unroll
            for (int ks = 0; ks < 4; ks++)
                #pragma unroll
                for (int cb = 0; cb < 4; cb++)
                    cz[cb] = __builtin_amdgcn_mfma_f32_16x16x32_bf16(a[ks], w1f[cb][ks], cz[cb], 0, 0, 0);
            #pragma unroll
            for (int ks = 0; ks < 2; ks++)
                #pragma unroll
                for (int cb = 0; cb < 4; cb++) {
                    short8 bg = *(const short8*)&wTg[(cb * 16 + m) * 72 + ks * 32 + quad * 8];
                    cd[cb] = __builtin_amdgcn_mfma_f32_16x16x32_bf16(a[2 + ks], bg, cd[cb], 0, 0, 0);
                }
            #pragma unroll
            for (int cb = 0; cb < 4; cb++) {
                int feat = cb * 16 + m;
                #pragma unroll
                for (int r = 0; r < 4; r++) {
                    int n = n0 + quad * 4 + r;
                    zsw[(long)n * 128 + feat] = f2b(cz[cb][r]);
                    zsw[(long)n * 128 + 64 + feat] = f2b(cd[cb][r] * dinv[n]);
                }
            }
        }
        __syncthreads();
    }
}

// ---------------- mmC: x'=relu(hB@W2+b2); wout=[x',s]@Whp+bw; pool into xp ----------------
__global__ __launch_bounds__(256) void k_mmC(const bf16* __restrict__ hB,
                                             const bf16* __restrict__ s,
                                             const void* __restrict__ W2,
                                             const void* __restrict__ B2,
                                             const void* __restrict__ Ww,
                                             const void* __restrict__ Bw,
                                             const int* __restrict__ batch,
                                             const int* __restrict__ flags,
                                             long w2_off, long b2_off,
                                             float* __restrict__ xp) {
    __shared__ short wT2[64 * 72];
    __shared__ short wTw[64 * 136];
    __shared__ float bl2[64], blw[64];
    __shared__ short xbuf[4][16 * 72];
    const int isf32 = flags[0];
    const int i64 = flags[1];
    const int tid = threadIdx.x;
    for (int i = tid; i < 64 * 64; i += 256) {
        int k = i >> 6, f = i & 63;
        wT2[f * 72 + k] = f2bs(ldf(W2, w2_off + i, isf32));
    }
    for (int i = tid; i < 64 * 128; i += 256) {
        int k = i >> 6, f = i & 63;
        wTw[f * 136 + k] = f2bs(ldf(Ww, i, isf32));
    }
    if (tid < 64) { bl2[tid] = ldf(B2, b2_off + tid, isf32); blw[tid] = ldf(Bw, tid, isf32); }
    __syncthreads();

    const int lane = tid & 63, wv = tid >> 6;
    const int m = lane & 15, quad = lane >> 4;

    short8 w2f[4][2], wwf[4][4];
    #pragma unroll
    for (int cb = 0; cb < 4; cb++) {
        #pragma unroll
        for (int ks = 0; ks < 2; ks++)
            w2f[cb][ks] = *(const short8*)&wT2[(cb * 16 + m) * 72 + ks * 32 + quad * 8];
        #pragma unroll
        for (int ks = 0; ks < 4; ks++)
            wwf[cb][ks] = *(const short8*)&wTw[(cb * 16 + m) * 136 + ks * 32 + quad * 8];
    }

    for (int base = blockIdx.x * 4; base < NTILES; base += gridDim.x * 4) {
        int t = base + wv;
        bool valid = (t < NTILES);
        int n0 = t * 16;
        if (valid) {
            short8 ah[2];
            ah[0] = *(const short8*)&hB[(long)(n0 + m) * 64 + quad * 8];
            ah[1] = *(const short8*)&hB[(long)(n0 + m) * 64 + 32 + quad * 8];
            float4v cx[4];
            #pragma unroll
            for (int cb = 0; cb < 4; cb++) { cx[cb][0]=0.f; cx[cb][1]=0.f; cx[cb][2]=0.f; cx[cb][3]=0.f; }
            #pragma unroll
            for (int ks = 0; ks < 2; ks++)
                #pragma unroll
                for (int cb = 0; cb < 4; cb++)
                    cx[cb] = __builtin_amdgcn_mfma_f32_16x16x32_bf16(ah[ks], w2f[cb][ks], cx[cb], 0, 0, 0);
            #pragma unroll
            for (int cb = 0; cb < 4; cb++) {
                int feat = cb * 16 + m;
                float bb = bl2[feat];
                #pragma unroll
                for (int r = 0; r < 4; r++)
                    xbuf[wv][(quad * 4 + r) * 72 + feat] = f2bs(fmaxf(cx[cb][r] + bb, 0.f));
            }
        }
        __syncthreads();
        if (valid) {
            short8 a[4];
            a[0] = *(const short8*)&xbuf[wv][m * 72 + quad * 8];
            a[1] = *(const short8*)&xbuf[wv][m * 72 + 32 + quad * 8];
            a[2] = *(const short8*)&s[(long)(n0 + m) * 64 + quad * 8];
            a[3] = *(const short8*)&s[(long)(n0 + m) * 64 + 32 + quad * 8];
            float4v cz[4];
            #pragma unroll
            for (int cb = 0; cb < 4; cb++) { cz[cb][0]=0.f; cz[cb][1]=0.f; cz[cb][2]=0.f; cz[cb][3]=0.f; }
            #pragma unroll
            for (int ks = 0; ks < 4; ks++)
                #pragma unroll
                for (int cb = 0; cb < 4; cb++)
                    cz[cb] = __builtin_amdgcn_mfma_f32_16x16x32_bf16(a[ks], wwf[cb][ks], cz[cb], 0, 0, 0);
            int g[4];
            #pragma unroll
            for (int r = 0; r < 4; r++) g[r] = geti(batch, n0 + quad * 4 + r, i64);
            #pragma unroll
            for (int cb = 0; cb < 4; cb++) {
                int feat = cb * 16 + m;
                float bw = blw[feat];
                int gp = g[0];
                float acc = cz[cb][0] + bw;
                #pragma unroll
                for (int r = 1; r < 4; r++) {
                    if (g[r] == gp) acc += cz[cb][r] + bw;
                    else { atomicAdd(&xp[(long)gp * 64 + feat], acc); gp = g[r]; acc = cz[cb][r] + bw; }
                }
                atomicAdd(&xp[(long)gp * 64 + feat], acc);
            }
        }
        __syncthreads();
    }
}

// ---------------- fused GIN+GCN gather ----------------
__global__ __launch_bounds__(256) void k_gather2(const uint* __restrict__ zsw,
                                                 const int* __restrict__ row_end,
                                                 const int* __restrict__ deg,
                                                 const int* __restrict__ csr_src,
                                                 const void* __restrict__ b1,
                                                 const void* __restrict__ bg,
                                                 const float* __restrict__ dinv,
                                                 const int* __restrict__ flags,
                                                 long b_off,
                                                 uint* __restrict__ hB,
                                                 uint* __restrict__ sOut) {
    int tid = threadIdx.x;
    int wv = tid >> 6, lane = tid & 63;
    int half = lane >> 5, fl = lane & 31;
    int isf32 = flags[0];
    float bb0, bb1;
    if (half == 0) {
        bb0 = ldf(b1, b_off + 2 * fl, isf32);
        bb1 = ldf(b1, b_off + 2 * fl + 1, isf32);
    } else {
        bb0 = ldf(bg, b_off + 2 * fl, isf32);
        bb1 = ldf(bg, b_off + 2 * fl + 1, isf32);
    }
    int n = blockIdx.x * 4 + wv;
    if (n >= N_NODES) return;
    int end = row_end[n], beg = end - deg[n];
    uint u = zsw[(long)n * 64 + lane];
    float a0 = bflo(u), a1 = bfhi(u);
    int p = beg;
    for (; p + 8 <= end; p += 8) {
        int i0 = csr_src[p], i1 = csr_src[p + 1], i2 = csr_src[p + 2], i3 = csr_src[p + 3];
        int i4 = csr_src[p + 4], i5 = csr_src[p + 5], i6 = csr_src[p + 6], i7 = csr_src[p + 7];
        uint u0 = zsw[(long)i0 * 64 + lane], u1 = zsw[(long)i1 * 64 + lane];
        uint u2 = zsw[(long)i2 * 64 + lane], u3 = zsw[(long)i3 * 64 + lane];
        uint u4 = zsw[(long)i4 * 64 + lane], u5 = zsw[(long)i5 * 64 + lane];
        uint u6 = zsw[(long)i6 * 64 + lane], u7 = zsw[(long)i7 * 64 + lane];
        a0 += ((bflo(u0) + bflo(u1)) + (bflo(u2) + bflo(u3)))
            + ((bflo(u4) + bflo(u5)) + (bflo(u6) + bflo(u7)));
        a1 += ((bfhi(u0) + bfhi(u1)) + (bfhi(u2) + bfhi(u3)))
            + ((bfhi(u4) + bfhi(u5)) + (bfhi(u6) + bfhi(u7)));
    }
    for (; p < end; p++) {
        uint uu = zsw[(long)csr_src[p] * 64 + lane];
        a0 += bflo(uu); a1 += bfhi(uu);
    }
    if (half == 0) {
        hB[(long)n * 32 + fl] = packbf(fmaxf(a0 + bb0, 0.f), fmaxf(a1 + bb1, 0.f));
    } else {
        float dn = dinv[n];
        sOut[(long)n * 32 + fl] = packbf(tanhf(dn * a0 + bb0), tanhf(dn * a1 + bb1));
    }
}

// ---------------- final: post + readout + log_softmax ----------------
__global__ __launch_bounds__(64) void k_final(const float* __restrict__ xp,
                                              const void* __restrict__ post_w,
                                              const void* __restrict__ post_b,
                                              const void* __restrict__ ro_w,
                                              const void* __restrict__ ro_b,
                                              const int* __restrict__ flags,
                                              void* __restrict__ out) {
    __shared__ float h2[64];
    __shared__ float lg[16];
    int isf32 = flags[0];
    int g = blockIdx.x;
    int f = threadIdx.x;
    float xr = xp[(long)g * 64 + f];
    float acc = ldf(post_b, f, isf32);
    #pragma unroll
    for (int j = 0; j < 64; j++) acc += __shfl(xr, j) * ldf(post_w, j * 64 + f, isf32);
    float v = fmaxf(acc, 0.f);
    h2[f] = v;
    long oxp = (long)g * 64 + f;
    if (isf32) ((float*)out)[oxp] = v; else ((bf16*)out)[oxp] = f2b(v);
    __syncthreads();
    if (f < 16) {
        float a = ldf(ro_b, f, isf32);
        for (int j = 0; j < 64; j++) a += h2[j] * ldf(ro_w, j * 16 + f, isf32);
        lg[f] = a;
    }
    __syncthreads();
    if (f < 16) {
        float m = -1e30f;
        for (int j = 0; j < 16; j++) m = fmaxf(m, lg[j]);
        float sum = 0.f;
        for (int j = 0; j < 16; j++) sum += expf(lg[j] - m);
        long oy = (long)N_GRAPHS * 64 + (long)g * 16 + f;
        float yv = lg[f] - m - logf(sum);
        if (isf32) ((float*)out)[oy] = yv; else ((bf16*)out)[oy] = f2b(yv);
    }
}

extern "C" void kernel_launch(void* const* d_in, const int* in_sizes, int n_in,
                              void* d_out, int out_size, void* d_ws, size_t ws_size,
                              hipStream_t stream) {
    const void* x_in  = d_in[0];
    const void* s_in  = d_in[1];
    const int*  ei    = (const int*)d_in[2];
    const int*  batch = (const int*)d_in[3];
    const void* pre_w = d_in[4];
    const void* pre_b = d_in[5];
    const void* emb_w = d_in[6];
    const void* emb_b = d_in[7];
    const void* gin_w1 = d_in[8];
    const void* gin_b1 = d_in[9];
    const void* gin_w2 = d_in[10];
    const void* gin_b2 = d_in[11];
    const void* gcn_w  = d_in[12];
    const void* gcn_b  = d_in[13];
    const void* whp_w  = d_in[14];
    const void* whp_b  = d_in[15];
    const void* post_w = d_in[16];
    const void* post_b = d_in[17];
    const void* ro_w   = d_in[18];
    const void* ro_b   = d_in[19];

    // ws: flags(64) | deg(N) | row_end(N) | hist(NB1*NBUCK) | pexcl(NB1*NBUCK)
    //   | total(NBUCK) | bucket_base(NBUCK+1+pad) | bstore(E) | csr_src(E) | dinv(N)
    //   | x0,sA,hB (bf16 N*64) | zsw (uint N*64) | xp (f32 G*64)
    int* flags   = (int*)d_ws;
    int* deg     = flags + 64;
    int* row_end = deg + N_NODES;
    int* hist    = row_end + N_NODES;
    int* pexcl   = hist + NB1 * NBUCK;
    int* total   = pexcl + NB1 * NBUCK;
    int* bbase   = total + NBUCK;
    uint* bstore = (uint*)(bbase + NBUCK + 4);
    int* csr_src = (int*)(bstore + N_EDGES);
    float* dinv  = (float*)(csr_src + N_EDGES);
    bf16* x0     = (bf16*)(dinv + N_NODES);
    bf16* sA     = x0 + (long)N_NODES * 64;
    bf16* hB     = sA + (long)N_NODES * 64;
    uint* zsw    = (uint*)(hB + (long)N_NODES * 64);
    float* xp    = (float*)(zsw + (long)N_NODES * 64);

    const int MMB = 512;
    const int GGB = (N_NODES + 3) / 4;       // 25000

    k_detect<<<1, 64, 0, stream>>>(x_in, ei, flags);

    // CSR + deg + dinv + row_end: two-pass radix partition
    k1_hist<<<NB1, 256, 0, stream>>>(ei, flags, hist);
    k2a<<<NBUCK, 256, 0, stream>>>(hist, pexcl, total);
    k2b<<<1, 256, 0, stream>>>(total, bbase);
    k3_scatter<<<NB1, 256, 0, stream>>>(ei, flags, pexcl, bbase, bstore);
    k4_csr<<<NBUCK, 256, 0, stream>>>(bstore, bbase, deg, dinv, row_end, csr_src);

    const long W1 = 128 * 64, W2 = 64 * 64, WG = 64 * 64, B = 64;

    // pre / embedding -> bf16 activations
    k_mm_in<128, 128><<<MMB, 256, 0, stream>>>(x_in, pre_w, pre_b, flags, x0);
    k_mm_in<32, 16><<<MMB, 256, 0, stream>>>(s_in, emb_w, emb_b, flags, sA);

    // ---- layer 0 ----
    k_mmA<<<MMB, 256, 0, stream>>>(x0, sA, gin_w1, gcn_w, dinv, flags, 0L, 0L, (bf16*)zsw);
    k_gather2<<<GGB, 256, 0, stream>>>(zsw, row_end, deg, csr_src, gin_b1, gcn_b, dinv, flags, 0L, (uint*)hB, (uint*)sA);

    // ---- layer 0 tail fused with layer 1 head ----
    k_mmB<<<MMB, 256, 0, stream>>>(hB, sA, gin_w2, gin_b2, gin_w1, gcn_w, dinv, flags,
                                   0L, 0L, W1, WG, (bf16*)zsw);
    k_gather2<<<GGB, 256, 0, stream>>>(zsw, row_end, deg, csr_src, gin_b1, gcn_b, dinv, flags, B, (uint*)hB, (uint*)sA);

    // ---- layer 1 tail + whp + pool ----
    hipMemsetAsync(xp, 0, (size_t)N_GRAPHS * 64 * sizeof(float), stream);
    k_mmC<<<MMB, 256, 0, stream>>>(hB, sA, gin_w2, gin_b2, whp_w, whp_b, batch, flags,
                                   W2, B, xp);

    k_final<<<N_GRAPHS, 64, 0, stream>>>(xp, post_w, post_b, ro_w, ro_b, flags, d_out);
}